// Round 4
// baseline (11297.446 us; speedup 1.0000x reference)
//
#include <hip/hip_runtime.h>
#include <cstddef>

#define TT 16
#define NNODES 20000
#define EE 80000
#define BE 320000
#define EB 340000
#define NPER 5000
#define NB 512
#define NTHREADS (NB * 256)
#define NW (NB * 4)

typedef __attribute__((ext_vector_type(8))) short bf16x8;
typedef __attribute__((ext_vector_type(4))) float f32x4;

__device__ __forceinline__ float sigf(float x) { return 1.0f / (1.0f + __expf(-x)); }
__device__ __forceinline__ float lreluf(float x) { return x > 0.0f ? x : 0.2f * x; }

__device__ __forceinline__ unsigned short f2bf(float x) {
  union { float f; unsigned u; } v; v.f = x;
  unsigned r = v.u + 0x7FFF + ((v.u >> 16) & 1);
  return (unsigned short)(r >> 16);
}
__device__ __forceinline__ float bf2f(unsigned short u) {
  union { unsigned u; float f; } v; v.u = ((unsigned)u) << 16; return v.f;
}
__device__ __forceinline__ f32x4 mfma16(bf16x8 a, bf16x8 b, f32x4 c) {
  return __builtin_amdgcn_mfma_f32_16x16x32_bf16(a, b, c, 0, 0, 0);
}

struct P {
  const float *x_seq, *att_src, *att_dst, *gat_bias, *ln_g, *ln_b, *b1, *w2, *b2;
  const float *lin_w, *w_ih, *w_hh, *b_ih, *b_hh, *w1;
  const int* eidx;
  float* out;
  // workspace
  float *c_st, *xt, *asrc, *adst, *bsum;
  unsigned short *hH, *hL, *spH, *spL;
  unsigned short *linH, *linL, *wihH, *wihL, *whhH, *whhL, *w1H, *w1L;
  int *deg, *cnt, *startp, *adj, *csum, *cbase;
  int *bar_cnt, *bar_gen;
};

// ---- device-scope grid barrier (all NB blocks co-resident via launch_bounds) ----
__device__ __forceinline__ void gbar(int* cnt, int* gen) {
  __syncthreads();
  if (threadIdx.x == 0) {
    int g = __hip_atomic_load(gen, __ATOMIC_RELAXED, __HIP_MEMORY_SCOPE_AGENT);
    int v = __hip_atomic_fetch_add(cnt, 1, __ATOMIC_ACQ_REL, __HIP_MEMORY_SCOPE_AGENT);
    if (v == NB - 1) {
      __hip_atomic_store(cnt, 0, __ATOMIC_RELAXED, __HIP_MEMORY_SCOPE_AGENT);
      __hip_atomic_store(gen, g + 1, __ATOMIC_RELEASE, __HIP_MEMORY_SCOPE_AGENT);
    } else {
      while (__hip_atomic_load(gen, __ATOMIC_ACQUIRE, __HIP_MEMORY_SCOPE_AGENT) == g)
        __builtin_amdgcn_s_sleep(2);
    }
  }
  __syncthreads();
}

// ---- phase A: xt GEMM (split bf16) + GAT attention coefficients ----
__device__ void phaseA(const P& p, int cell, int rb, int t, int lane) {
  const int l15 = lane & 15, lg = lane >> 4;
  const int m0 = rb * 16;
  const int gm = m0 + l15;
  const float* A = p.x_seq + (size_t)t * 1280000;
  const unsigned short* WH = p.linH + cell * 4096;
  const unsigned short* WL = p.linL + cell * 4096;
  const float* attS = p.att_src + cell * 64;
  const float* attD = p.att_dst + cell * 64;
  float* xtC = p.xt + (size_t)cell * 1280000;
  float* asrcC = p.asrc + (size_t)cell * 80000;
  float* adstC = p.adst + (size_t)cell * 80000;

  const float* arow = A + (size_t)gm * 64;
  bf16x8 aH[2], aL[2];
#pragma unroll
  for (int ch = 0; ch < 2; ++ch) {
    float4 u0 = *reinterpret_cast<const float4*>(arow + ch * 32 + lg * 8);
    float4 u1 = *reinterpret_cast<const float4*>(arow + ch * 32 + lg * 8 + 4);
    float v[8] = {u0.x, u0.y, u0.z, u0.w, u1.x, u1.y, u1.z, u1.w};
    bf16x8 th, tl;
#pragma unroll
    for (int i = 0; i < 8; ++i) {
      unsigned short hi = f2bf(v[i]);
      th[i] = (short)hi;
      tl[i] = (short)f2bf(v[i] - bf2f(hi));
    }
    aH[ch] = th; aL[ch] = tl;
  }
  f32x4 acc[4];
#pragma unroll
  for (int nf = 0; nf < 4; ++nf) acc[nf] = (f32x4){0.f, 0.f, 0.f, 0.f};
#pragma unroll
  for (int nf = 0; nf < 4; ++nf) {
#pragma unroll
    for (int ch = 0; ch < 2; ++ch) {
      size_t wo = (size_t)(nf * 16 + l15) * 64 + ch * 32 + lg * 8;
      bf16x8 bH = *reinterpret_cast<const bf16x8*>(WH + wo);
      bf16x8 bL = *reinterpret_cast<const bf16x8*>(WL + wo);
      acc[nf] = mfma16(aH[ch], bH, acc[nf]);
      acc[nf] = mfma16(aH[ch], bL, acc[nf]);
      acc[nf] = mfma16(aL[ch], bH, acc[nf]);
    }
  }
#pragma unroll
  for (int nf = 0; nf < 4; ++nf) {
    float sv = attS[nf * 16 + l15], dv = attD[nf * 16 + l15];
#pragma unroll
    for (int r = 0; r < 4; ++r) {
      int row = m0 + lg * 4 + r;
      float v = acc[nf][r];
      float ps = v * sv, pd = v * dv;
#pragma unroll
      for (int off = 1; off < 16; off <<= 1) { ps += __shfl_xor(ps, off); pd += __shfl_xor(pd, off); }
      xtC[(size_t)row * 64 + nf * 16 + l15] = v;
      if (l15 == 0) { asrcC[row * 4 + nf] = ps; adstC[row * 4 + nf] = pd; }
    }
  }
}

// ---- phase B: edge softmax + aggregation (wave per node, 4-edge-parallel PV) ----
__device__ void phaseB(const P& p, int cell, int node, int lane) {
  int s0 = p.startp[node];
  int dg = p.startp[node + 1] - s0;
  const float* asrcC = p.asrc + (size_t)cell * 80000;
  const float* xtC = p.xt + (size_t)cell * 1280000;
  float4 adv = *reinterpret_cast<const float4*>(p.adst + (size_t)cell * 80000 + (size_t)node * 4);
  float ad0 = adv.x, ad1 = adv.y, ad2 = adv.z, ad3 = adv.w;

  float mx0 = -1e30f, mx1 = -1e30f, mx2 = -1e30f, mx3 = -1e30f;
  for (int e = lane; e < dg; e += 64) {
    int src = p.adj[s0 + e];
    float4 av = *reinterpret_cast<const float4*>(asrcC + (size_t)src * 4);
    mx0 = fmaxf(mx0, lreluf(av.x + ad0));
    mx1 = fmaxf(mx1, lreluf(av.y + ad1));
    mx2 = fmaxf(mx2, lreluf(av.z + ad2));
    mx3 = fmaxf(mx3, lreluf(av.w + ad3));
  }
#pragma unroll
  for (int off = 1; off < 64; off <<= 1) {
    mx0 = fmaxf(mx0, __shfl_xor(mx0, off));
    mx1 = fmaxf(mx1, __shfl_xor(mx1, off));
    mx2 = fmaxf(mx2, __shfl_xor(mx2, off));
    mx3 = fmaxf(mx3, __shfl_xor(mx3, off));
  }
  float dn0 = 0.f, dn1 = 0.f, dn2 = 0.f, dn3 = 0.f;
  for (int e = lane; e < dg; e += 64) {
    int src = p.adj[s0 + e];
    float4 av = *reinterpret_cast<const float4*>(asrcC + (size_t)src * 4);
    dn0 += __expf(lreluf(av.x + ad0) - mx0);
    dn1 += __expf(lreluf(av.y + ad1) - mx1);
    dn2 += __expf(lreluf(av.z + ad2) - mx2);
    dn3 += __expf(lreluf(av.w + ad3) - mx3);
  }
#pragma unroll
  for (int off = 1; off < 64; off <<= 1) {
    dn0 += __shfl_xor(dn0, off);
    dn1 += __shfl_xor(dn1, off);
    dn2 += __shfl_xor(dn2, off);
    dn3 += __shfl_xor(dn3, off);
  }
  float rd0 = 1.0f / (dn0 + 1e-16f), rd1 = 1.0f / (dn1 + 1e-16f);
  float rd2 = 1.0f / (dn2 + 1e-16f), rd3 = 1.0f / (dn3 + 1e-16f);

  int g = lane >> 4, c = lane & 15;
  float a0 = 0.f, a1 = 0.f, a2 = 0.f, a3 = 0.f;
  for (int e = g; e < dg; e += 4) {
    int src = p.adj[s0 + e];
    float4 av = *reinterpret_cast<const float4*>(asrcC + (size_t)src * 4);
    const float* xr = xtC + (size_t)src * 64;
    a0 = fmaf(__expf(lreluf(av.x + ad0) - mx0) * rd0, xr[c], a0);
    a1 = fmaf(__expf(lreluf(av.y + ad1) - mx1) * rd1, xr[c + 16], a1);
    a2 = fmaf(__expf(lreluf(av.z + ad2) - mx2) * rd2, xr[c + 32], a2);
    a3 = fmaf(__expf(lreluf(av.w + ad3) - mx3) * rd3, xr[c + 48], a3);
  }
  a0 += __shfl_xor(a0, 16); a0 += __shfl_xor(a0, 32);
  a1 += __shfl_xor(a1, 16); a1 += __shfl_xor(a1, 32);
  a2 += __shfl_xor(a2, 16); a2 += __shfl_xor(a2, 32);
  a3 += __shfl_xor(a3, 16); a3 += __shfl_xor(a3, 32);
  float v = (g == 0) ? a0 : ((g == 1) ? a1 : ((g == 2) ? a2 : a3));
  int col = c + 16 * g;
  v += p.gat_bias[cell * 64 + col];
  unsigned short hi = f2bf(v);
  size_t o = (size_t)cell * 1280000 + (size_t)node * 64 + col;
  p.spH[o] = hi;
  p.spL[o] = f2bf(v - bf2f(hi));
}

// ---- mix core: [hf|hm|hs] @ w1^T -> relu -> @ w2^T -> softmax3 -> blend ----
__device__ void mix_core(const P& p, int rb, int t, int lane, const float* hldsw) {
  const int l15 = lane & 15, lg = lane >> 4;
  const int m0 = rb * 16;
  const int gm = m0 + l15;
  const unsigned short* hHs_[3] = { p.hH, p.hH + 1280000, p.hH + 2560000 };
  const unsigned short* hLs_[3] = { p.hL, p.hL + 1280000, p.hL + 2560000 };
  bf16x8 aH[3][2], aL[3][2];
#pragma unroll
  for (int ch = 0; ch < 2; ++ch) {
    if (hldsw) {
      bf16x8 th, tl;
#pragma unroll
      for (int i = 0; i < 8; ++i) {
        float v = hldsw[l15 * 68 + ch * 32 + lg * 8 + i];
        unsigned short hi = f2bf(v);
        th[i] = (short)hi;
        tl[i] = (short)f2bf(v - bf2f(hi));
      }
      aH[0][ch] = th; aL[0][ch] = tl;
    } else {
      size_t off = (size_t)gm * 64 + ch * 32 + lg * 8;
      aH[0][ch] = *reinterpret_cast<const bf16x8*>(hHs_[0] + off);
      aL[0][ch] = *reinterpret_cast<const bf16x8*>(hLs_[0] + off);
    }
    size_t off = (size_t)gm * 64 + ch * 32 + lg * 8;
    aH[1][ch] = *reinterpret_cast<const bf16x8*>(hHs_[1] + off);
    aL[1][ch] = *reinterpret_cast<const bf16x8*>(hLs_[1] + off);
    aH[2][ch] = *reinterpret_cast<const bf16x8*>(hHs_[2] + off);
    aL[2][ch] = *reinterpret_cast<const bf16x8*>(hLs_[2] + off);
  }
  f32x4 acc[6];
#pragma unroll
  for (int nf = 0; nf < 6; ++nf) acc[nf] = (f32x4){0.f, 0.f, 0.f, 0.f};
#pragma unroll
  for (int nf = 0; nf < 6; ++nf) {
#pragma unroll
    for (int s = 0; s < 3; ++s) {
#pragma unroll
      for (int ch = 0; ch < 2; ++ch) {
        size_t wo = (size_t)(nf * 16 + l15) * 192 + s * 64 + ch * 32 + lg * 8;
        bf16x8 bH = *reinterpret_cast<const bf16x8*>(p.w1H + wo);
        bf16x8 bL = *reinterpret_cast<const bf16x8*>(p.w1L + wo);
        acc[nf] = mfma16(aH[s][ch], bH, acc[nf]);
        acc[nf] = mfma16(aH[s][ch], bL, acc[nf]);
        acc[nf] = mfma16(aL[s][ch], bH, acc[nf]);
      }
    }
  }
#pragma unroll
  for (int r = 0; r < 4; ++r) {
    float p0 = 0.f, p1 = 0.f, p2 = 0.f;
#pragma unroll
    for (int nf = 0; nf < 6; ++nf) {
      int n = nf * 16 + l15;
      float hdv = fmaxf(acc[nf][r] + p.b1[n], 0.f);
      p0 = fmaf(hdv, p.w2[n], p0);
      p1 = fmaf(hdv, p.w2[96 + n], p1);
      p2 = fmaf(hdv, p.w2[192 + n], p2);
    }
#pragma unroll
    for (int off = 1; off < 16; off <<= 1) {
      p0 += __shfl_xor(p0, off); p1 += __shfl_xor(p1, off); p2 += __shfl_xor(p2, off);
    }
    float q0 = p0 + p.b2[0], q1 = p1 + p.b2[1], q2 = p2 + p.b2[2];
    float mx = fmaxf(q0, fmaxf(q1, q2));
    float e0 = __expf(q0 - mx), e1 = __expf(q1 - mx), e2 = __expf(q2 - mx);
    float rs = 1.0f / (e0 + e1 + e2);
    float w0 = e0 * rs, w1v = e1 * rs, w2v = e2 * rs;
    int row = m0 + lg * 4 + r;
    size_t ob = ((size_t)row * TT + t) * 64;
    size_t hb = (size_t)row * 64;
#pragma unroll
    for (int q = 0; q < 4; ++q) {
      int col = l15 + 16 * q;
      float vf = hldsw ? hldsw[(lg * 4 + r) * 68 + col]
                       : (bf2f(hHs_[0][hb + col]) + bf2f(hLs_[0][hb + col]));
      float vm = bf2f(hHs_[1][hb + col]) + bf2f(hLs_[1][hb + col]);
      float vs = bf2f(hHs_[2][hb + col]) + bf2f(hLs_[2][hb + col]);
      p.out[ob + col] = w0 * vf + w1v * vm + w2v * vs;
    }
  }
}

// ---- phase C: gates GEMM + LSTM pointwise + LayerNorm (+ fused mix) ----
__device__ void phaseC(const P& p, int cell, int rb, int t, bool fused, int lane, float* hldsw) {
  const int l15 = lane & 15, lg = lane >> 4;
  const int m0 = rb * 16;
  const int gm = m0 + l15;
  size_t cs = (size_t)cell * 1280000;
  const unsigned short* spH = p.spH + cs;
  const unsigned short* spL = p.spL + cs;
  unsigned short* hH = p.hH + cs;
  unsigned short* hL = p.hL + cs;
  const unsigned short* WihH = p.wihH + cell * 16384;
  const unsigned short* WihL = p.wihL + cell * 16384;
  const unsigned short* WhhH = p.whhH + cell * 16384;
  const unsigned short* WhhL = p.whhL + cell * 16384;
  const float* bsum = p.bsum + cell * 256;
  float* cst = p.c_st + cs;
  const float* g_ln = p.ln_g + cell * 64;
  const float* b_ln = p.ln_b + cell * 64;

  bf16x8 sHa[2], sLa[2], hHa[2], hLa[2];
#pragma unroll
  for (int ch = 0; ch < 2; ++ch) {
    size_t off = (size_t)gm * 64 + ch * 32 + lg * 8;
    sHa[ch] = *reinterpret_cast<const bf16x8*>(spH + off);
    sLa[ch] = *reinterpret_cast<const bf16x8*>(spL + off);
    hHa[ch] = *reinterpret_cast<const bf16x8*>(hH + off);
    hLa[ch] = *reinterpret_cast<const bf16x8*>(hL + off);
  }
  f32x4 acc[16];
#pragma unroll
  for (int nf = 0; nf < 16; ++nf) acc[nf] = (f32x4){0.f, 0.f, 0.f, 0.f};
#pragma unroll
  for (int nf = 0; nf < 16; ++nf) {
#pragma unroll
    for (int ch = 0; ch < 2; ++ch) {
      size_t wo = (size_t)(nf * 16 + l15) * 64 + ch * 32 + lg * 8;
      bf16x8 bH = *reinterpret_cast<const bf16x8*>(WihH + wo);
      bf16x8 bL = *reinterpret_cast<const bf16x8*>(WihL + wo);
      acc[nf] = mfma16(sHa[ch], bH, acc[nf]);
      acc[nf] = mfma16(sHa[ch], bL, acc[nf]);
      acc[nf] = mfma16(sLa[ch], bH, acc[nf]);
      bf16x8 cH = *reinterpret_cast<const bf16x8*>(WhhH + wo);
      bf16x8 cL = *reinterpret_cast<const bf16x8*>(WhhL + wo);
      acc[nf] = mfma16(hHa[ch], cH, acc[nf]);
      acc[nf] = mfma16(hHa[ch], cL, acc[nf]);
      acc[nf] = mfma16(hLa[ch], cH, acc[nf]);
    }
  }
  float hn[4][4], cn[4][4];
#pragma unroll
  for (int cq = 0; cq < 4; ++cq) {
    int col = cq * 16 + l15;
    float bi = bsum[col], bff = bsum[64 + col], bg = bsum[128 + col], bo = bsum[192 + col];
#pragma unroll
    for (int r = 0; r < 4; ++r) {
      int row = m0 + lg * 4 + r;
      float gi = acc[cq][r] + bi;
      float gf = acc[cq + 4][r] + bff;
      float gg = acc[cq + 8][r] + bg;
      float go = acc[cq + 12][r] + bo;
      float cold = cst[(size_t)row * 64 + col];
      float cv = sigf(gf) * cold + sigf(gi) * tanhf(gg);
      cn[cq][r] = cv;
      hn[cq][r] = sigf(go) * tanhf(cv);
    }
  }
#pragma unroll
  for (int r = 0; r < 4; ++r) {
    float s = hn[0][r] + hn[1][r] + hn[2][r] + hn[3][r];
#pragma unroll
    for (int off = 1; off < 16; off <<= 1) s += __shfl_xor(s, off);
    float mu = s * (1.0f / 64.0f);
    float vv = 0.f;
#pragma unroll
    for (int cq = 0; cq < 4; ++cq) { float d = hn[cq][r] - mu; vv += d * d; }
#pragma unroll
    for (int off = 1; off < 16; off <<= 1) vv += __shfl_xor(vv, off);
    float rstd = rsqrtf(vv * (1.0f / 64.0f) + 1e-5f);
    int row = m0 + lg * 4 + r;
#pragma unroll
    for (int cq = 0; cq < 4; ++cq) {
      int col = cq * 16 + l15;
      float hl = (hn[cq][r] - mu) * rstd * g_ln[col] + b_ln[col];
      unsigned short hi = f2bf(hl);
      hH[(size_t)row * 64 + col] = hi;
      hL[(size_t)row * 64 + col] = f2bf(hl - bf2f(hi));
      cst[(size_t)row * 64 + col] = cn[cq][r];
      if (fused) hldsw[(lg * 4 + r) * 68 + col] = hl;
    }
  }
  if (fused) {
    // same-wave LDS RAW; compiler inserts lgkmcnt before dependent ds_reads
    mix_core(p, rb, t, lane, hldsw);
  }
}

// ---- the mega kernel ----
__global__ __launch_bounds__(256, 2) void mega(P p) {
  const int tid = threadIdx.x;
  const int lane = tid & 63, wv = tid >> 6;
  const int wid = blockIdx.x * 4 + wv;
  const int gtid = blockIdx.x * 256 + tid;
  __shared__ float hlds[4][16][68];
  float* hldsw = &hlds[wv][0][0];
  int* bc = p.bar_cnt;
  int* bg = p.bar_gen;

  // ---- S0: zero state + counters; convert weights ----
  for (int i = gtid; i < 3840000; i += NTHREADS) p.c_st[i] = 0.f;
  unsigned int* hz = (unsigned int*)p.hH;   // hH(3)+hL(3) contiguous: 7.68M u16 = 3.84M u32
  for (int i = gtid; i < 3840000; i += NTHREADS) hz[i] = 0u;
  for (int i = gtid; i < NNODES + 8; i += NTHREADS) { p.deg[i] = 0; p.cnt[i] = 0; }
  for (int i = gtid; i < 49152; i += NTHREADS) {
    if (i < 12288) { float w = p.lin_w[i]; unsigned short h = f2bf(w); p.linH[i] = h; p.linL[i] = f2bf(w - bf2f(h)); }
    { float w = p.w_ih[i]; unsigned short h = f2bf(w); p.wihH[i] = h; p.wihL[i] = f2bf(w - bf2f(h)); }
    { float w = p.w_hh[i]; unsigned short h = f2bf(w); p.whhH[i] = h; p.whhL[i] = f2bf(w - bf2f(h)); }
    if (i < 18432) { float w = p.w1[i]; unsigned short h = f2bf(w); p.w1H[i] = h; p.w1L[i] = f2bf(w - bf2f(h)); }
    if (i < 768) p.bsum[i] = p.b_ih[i] + p.b_hh[i];
  }
  gbar(bc, bg);

  // ---- S1: degree count ----
  for (int e = gtid; e < EB; e += NTHREADS) {
    int dst;
    if (e < BE) { int r = e % EE; int b = e / EE; dst = p.eidx[EE + r] + b * NPER; }
    else dst = e - BE;
    atomicAdd(&p.deg[dst], 1);
  }
  gbar(bc, bg);

  // ---- S2: per-block chunk sums (40 nodes per block) ----
  if (wv == 0) {
    int n = blockIdx.x * 40 + lane;
    int v = (lane < 40 && n < NNODES) ? p.deg[n] : 0;
#pragma unroll
    for (int off = 1; off < 64; off <<= 1) v += __shfl_xor(v, off);
    if (lane == 0) p.csum[blockIdx.x] = v;
  }
  gbar(bc, bg);

  // ---- S3: block 0 scans 512 chunk sums ----
  if (blockIdx.x == 0 && wv == 0) {
    int s[8]; int tot = 0;
#pragma unroll
    for (int j = 0; j < 8; ++j) { s[j] = p.csum[lane * 8 + j]; tot += s[j]; }
    int inc = tot;
#pragma unroll
    for (int off = 1; off < 64; off <<= 1) { int u = __shfl_up(inc, off); if (lane >= off) inc += u; }
    int excl = inc - tot;
#pragma unroll
    for (int j = 0; j < 8; ++j) { p.cbase[lane * 8 + j] = excl; excl += s[j]; }
  }
  gbar(bc, bg);

  // ---- S4: per-block startp fill ----
  if (tid == 0) {
    int base_ = p.cbase[blockIdx.x];
    for (int i2 = 0; i2 < 40; ++i2) {
      int n = blockIdx.x * 40 + i2;
      if (n <= NNODES) { p.startp[n] = base_; if (n < NNODES) base_ += p.deg[n]; }
    }
  }
  gbar(bc, bg);

  // ---- S5: fill adjacency ----
  for (int e = gtid; e < EB; e += NTHREADS) {
    int src, dst;
    if (e < BE) { int r = e % EE; int b = e / EE; src = p.eidx[r] + b * NPER; dst = p.eidx[EE + r] + b * NPER; }
    else { src = e - BE; dst = src; }
    int pos = atomicAdd(&p.cnt[dst], 1);
    p.adj[p.startp[dst] + pos] = src;
  }
  gbar(bc, bg);

  // ---- main time loop ----
  for (int t = 0; t < TT; ++t) {
    const int ncell = (t == 0) ? 3 : ((t == 15) ? 2 : 1);
    for (int task = wid; task < ncell * 1250; task += NW)
      phaseA(p, task / 1250, task % 1250, t, lane);
    gbar(bc, bg);
    for (int task = wid; task < ncell * NNODES; task += NW)
      phaseB(p, task / NNODES, task % NNODES, lane);
    gbar(bc, bg);
    const bool fused = (ncell == 1);
    for (int task = wid; task < ncell * 1250; task += NW)
      phaseC(p, task / 1250, task % 1250, t, fused, lane, hldsw);
    gbar(bc, bg);
    if (!fused) {
      for (int task = wid; task < 1250; task += NW)
        mix_core(p, task, t, lane, nullptr);
      gbar(bc, bg);
    }
  }
}

// ---- host side ----
extern "C" void kernel_launch(void* const* d_in, const int* in_sizes, int n_in,
                              void* d_out, int out_size, void* d_ws, size_t ws_size,
                              hipStream_t stream) {
  P p;
  p.x_seq    = (const float*)d_in[0];
  p.lin_w    = (const float*)d_in[1];
  p.att_src  = (const float*)d_in[2];
  p.att_dst  = (const float*)d_in[3];
  p.gat_bias = (const float*)d_in[4];
  p.w_ih     = (const float*)d_in[5];
  p.w_hh     = (const float*)d_in[6];
  p.b_ih     = (const float*)d_in[7];
  p.b_hh     = (const float*)d_in[8];
  p.ln_g     = (const float*)d_in[9];
  p.ln_b     = (const float*)d_in[10];
  p.w1       = (const float*)d_in[11];
  p.b1       = (const float*)d_in[12];
  p.w2       = (const float*)d_in[13];
  p.b2       = (const float*)d_in[14];
  p.eidx     = (const int*)d_in[15];
  p.out      = (float*)d_out;

  char* base = (char*)d_ws;
  size_t off = 0;
  auto alloc = [&](size_t bytes) { char* r = base + off; off += (bytes + 255) & ~(size_t)255; return r; };
  p.c_st  = (float*)alloc(3840000 * 4);
  p.hH    = (unsigned short*)alloc(7680000 * 2);      // hH(3 planes) + hL(3 planes) contiguous
  p.hL    = p.hH + 3840000;
  p.xt    = (float*)alloc(3840000 * 4);
  p.spH   = (unsigned short*)alloc(3840000 * 2);
  p.spL   = (unsigned short*)alloc(3840000 * 2);
  p.asrc  = (float*)alloc(240000 * 4);
  p.adst  = (float*)alloc(240000 * 4);
  p.bsum  = (float*)alloc(768 * 4);
  p.linH  = (unsigned short*)alloc(12288 * 2);
  p.linL  = (unsigned short*)alloc(12288 * 2);
  p.wihH  = (unsigned short*)alloc(49152 * 2);
  p.wihL  = (unsigned short*)alloc(49152 * 2);
  p.whhH  = (unsigned short*)alloc(49152 * 2);
  p.whhL  = (unsigned short*)alloc(49152 * 2);
  p.w1H   = (unsigned short*)alloc(18432 * 2);
  p.w1L   = (unsigned short*)alloc(18432 * 2);
  p.deg   = (int*)alloc(20008 * 4);
  p.cnt   = (int*)alloc(20008 * 4);
  p.startp= (int*)alloc(20008 * 4);
  p.adj   = (int*)alloc(340000 * 4);
  p.csum  = (int*)alloc(512 * 4);
  p.cbase = (int*)alloc(512 * 4);
  int* barzone = (int*)alloc(256);
  p.bar_cnt = barzone;
  p.bar_gen = barzone + 16;

  hipMemsetAsync(barzone, 0, 256, stream);
  mega<<<NB, 256, 0, stream>>>(p);
}

// Round 5
// 4180.188 us; speedup vs baseline: 2.7026x; 2.7026x over previous
//
#include <hip/hip_runtime.h>
#include <cstddef>

#define TT 16
#define NNODES 20000
#define EE 80000
#define BE 320000
#define EB 340000
#define NPER 5000
#define NB 1024
#define NTHREADS (NB * 256)
#define NW (NB * 4)
#define NGRP 16
#define GSZ (NB / NGRP)
#define CHUNK 20

typedef __attribute__((ext_vector_type(8))) short bf16x8;
typedef __attribute__((ext_vector_type(4))) float f32x4;

__device__ __forceinline__ float sigf(float x) { return 1.0f / (1.0f + __expf(-x)); }
__device__ __forceinline__ float lreluf(float x) { return x > 0.0f ? x : 0.2f * x; }

__device__ __forceinline__ unsigned short f2bf(float x) {
  union { float f; unsigned u; } v; v.f = x;
  unsigned r = v.u + 0x7FFF + ((v.u >> 16) & 1);
  return (unsigned short)(r >> 16);
}
__device__ __forceinline__ float bf2f(unsigned short u) {
  union { unsigned u; float f; } v; v.u = ((unsigned)u) << 16; return v.f;
}
__device__ __forceinline__ f32x4 mfma16(bf16x8 a, bf16x8 b, f32x4 c) {
  return __builtin_amdgcn_mfma_f32_16x16x32_bf16(a, b, c, 0, 0, 0);
}

struct P {
  const float *x_seq, *att_src, *att_dst, *gat_bias, *ln_g, *ln_b, *b1, *w2, *b2;
  const float *lin_w, *w_ih, *w_hh, *b_ih, *b_hh, *w1;
  const int* eidx;
  float* out;
  float *c_st, *xt, *asrc, *adst, *bsum;
  unsigned short *hH, *hL, *spH, *spL;
  unsigned short *linH, *linL, *wihH, *wihL, *whhH, *whhL, *w1H, *w1L;
  int *deg, *cnt, *startp, *adj, *csum, *cbase;
  int *bar_grp, *bar_top, *bar_gen;
};

// ---- device-scope grid barrier: tree arrival, relaxed spin + single fences ----
__device__ __forceinline__ void gbar(const P& p) {
  __syncthreads();
  if (threadIdx.x == 0) {
    int g = __hip_atomic_load(p.bar_gen, __ATOMIC_RELAXED, __HIP_MEMORY_SCOPE_AGENT);
    int* gc = p.bar_grp + (blockIdx.x & (NGRP - 1)) * 64;
    int v = __hip_atomic_fetch_add(gc, 1, __ATOMIC_ACQ_REL, __HIP_MEMORY_SCOPE_AGENT);
    bool done = false;
    if (v == GSZ - 1) {
      __hip_atomic_store(gc, 0, __ATOMIC_RELAXED, __HIP_MEMORY_SCOPE_AGENT);
      int w = __hip_atomic_fetch_add(p.bar_top, 1, __ATOMIC_ACQ_REL, __HIP_MEMORY_SCOPE_AGENT);
      if (w == NGRP - 1) {
        __hip_atomic_store(p.bar_top, 0, __ATOMIC_RELAXED, __HIP_MEMORY_SCOPE_AGENT);
        __hip_atomic_store(p.bar_gen, g + 1, __ATOMIC_RELEASE, __HIP_MEMORY_SCOPE_AGENT);
        done = true;
      }
    }
    if (!done) {
      while (__hip_atomic_load(p.bar_gen, __ATOMIC_RELAXED, __HIP_MEMORY_SCOPE_AGENT) == g)
        __builtin_amdgcn_s_sleep(2);
      __builtin_amdgcn_fence(__ATOMIC_ACQUIRE, "agent");
    }
  }
  __syncthreads();
}

// ---- phase A: xt GEMM (split bf16) + GAT attention coefficients ----
__device__ void phaseA(const P& p, int cell, int rb, int t, int lane) {
  const int l15 = lane & 15, lg = lane >> 4;
  const int m0 = rb * 16;
  const int gm = m0 + l15;
  const float* A = p.x_seq + (size_t)t * 1280000;
  const unsigned short* WH = p.linH + cell * 4096;
  const unsigned short* WL = p.linL + cell * 4096;
  const float* attS = p.att_src + cell * 64;
  const float* attD = p.att_dst + cell * 64;
  float* xtC = p.xt + (size_t)cell * 1280000;
  float* asrcC = p.asrc + (size_t)cell * 80000;
  float* adstC = p.adst + (size_t)cell * 80000;

  const float* arow = A + (size_t)gm * 64;
  bf16x8 aH[2], aL[2];
#pragma unroll
  for (int ch = 0; ch < 2; ++ch) {
    float4 u0 = *reinterpret_cast<const float4*>(arow + ch * 32 + lg * 8);
    float4 u1 = *reinterpret_cast<const float4*>(arow + ch * 32 + lg * 8 + 4);
    float v[8] = {u0.x, u0.y, u0.z, u0.w, u1.x, u1.y, u1.z, u1.w};
    bf16x8 th, tl;
#pragma unroll
    for (int i = 0; i < 8; ++i) {
      unsigned short hi = f2bf(v[i]);
      th[i] = (short)hi;
      tl[i] = (short)f2bf(v[i] - bf2f(hi));
    }
    aH[ch] = th; aL[ch] = tl;
  }
  f32x4 acc[4];
#pragma unroll
  for (int nf = 0; nf < 4; ++nf) acc[nf] = (f32x4){0.f, 0.f, 0.f, 0.f};
#pragma unroll
  for (int nf = 0; nf < 4; ++nf) {
#pragma unroll
    for (int ch = 0; ch < 2; ++ch) {
      size_t wo = (size_t)(nf * 16 + l15) * 64 + ch * 32 + lg * 8;
      bf16x8 bH = *reinterpret_cast<const bf16x8*>(WH + wo);
      bf16x8 bL = *reinterpret_cast<const bf16x8*>(WL + wo);
      acc[nf] = mfma16(aH[ch], bH, acc[nf]);
      acc[nf] = mfma16(aH[ch], bL, acc[nf]);
      acc[nf] = mfma16(aL[ch], bH, acc[nf]);
    }
  }
#pragma unroll
  for (int nf = 0; nf < 4; ++nf) {
    float sv = attS[nf * 16 + l15], dv = attD[nf * 16 + l15];
#pragma unroll
    for (int r = 0; r < 4; ++r) {
      int row = m0 + lg * 4 + r;
      float v = acc[nf][r];
      float ps = v * sv, pd = v * dv;
#pragma unroll
      for (int off = 1; off < 16; off <<= 1) { ps += __shfl_xor(ps, off); pd += __shfl_xor(pd, off); }
      xtC[(size_t)row * 64 + nf * 16 + l15] = v;
      if (l15 == 0) { asrcC[row * 4 + nf] = ps; adstC[row * 4 + nf] = pd; }
    }
  }
}

// ---- phase B: edge softmax + aggregation (wave per node, 4-edge-parallel PV) ----
__device__ void phaseB(const P& p, int cell, int node, int lane) {
  int s0 = p.startp[node];
  int dg = p.startp[node + 1] - s0;
  const float* asrcC = p.asrc + (size_t)cell * 80000;
  const float* xtC = p.xt + (size_t)cell * 1280000;
  float4 adv = *reinterpret_cast<const float4*>(p.adst + (size_t)cell * 80000 + (size_t)node * 4);
  float ad0 = adv.x, ad1 = adv.y, ad2 = adv.z, ad3 = adv.w;

  float mx0 = -1e30f, mx1 = -1e30f, mx2 = -1e30f, mx3 = -1e30f;
  for (int e = lane; e < dg; e += 64) {
    int src = p.adj[s0 + e];
    float4 av = *reinterpret_cast<const float4*>(asrcC + (size_t)src * 4);
    mx0 = fmaxf(mx0, lreluf(av.x + ad0));
    mx1 = fmaxf(mx1, lreluf(av.y + ad1));
    mx2 = fmaxf(mx2, lreluf(av.z + ad2));
    mx3 = fmaxf(mx3, lreluf(av.w + ad3));
  }
#pragma unroll
  for (int off = 1; off < 64; off <<= 1) {
    mx0 = fmaxf(mx0, __shfl_xor(mx0, off));
    mx1 = fmaxf(mx1, __shfl_xor(mx1, off));
    mx2 = fmaxf(mx2, __shfl_xor(mx2, off));
    mx3 = fmaxf(mx3, __shfl_xor(mx3, off));
  }
  float dn0 = 0.f, dn1 = 0.f, dn2 = 0.f, dn3 = 0.f;
  for (int e = lane; e < dg; e += 64) {
    int src = p.adj[s0 + e];
    float4 av = *reinterpret_cast<const float4*>(asrcC + (size_t)src * 4);
    dn0 += __expf(lreluf(av.x + ad0) - mx0);
    dn1 += __expf(lreluf(av.y + ad1) - mx1);
    dn2 += __expf(lreluf(av.z + ad2) - mx2);
    dn3 += __expf(lreluf(av.w + ad3) - mx3);
  }
#pragma unroll
  for (int off = 1; off < 64; off <<= 1) {
    dn0 += __shfl_xor(dn0, off);
    dn1 += __shfl_xor(dn1, off);
    dn2 += __shfl_xor(dn2, off);
    dn3 += __shfl_xor(dn3, off);
  }
  float rd0 = 1.0f / (dn0 + 1e-16f), rd1 = 1.0f / (dn1 + 1e-16f);
  float rd2 = 1.0f / (dn2 + 1e-16f), rd3 = 1.0f / (dn3 + 1e-16f);

  int g = lane >> 4, c = lane & 15;
  float a0 = 0.f, a1 = 0.f, a2 = 0.f, a3 = 0.f;
  for (int e = g; e < dg; e += 4) {
    int src = p.adj[s0 + e];
    float4 av = *reinterpret_cast<const float4*>(asrcC + (size_t)src * 4);
    const float* xr = xtC + (size_t)src * 64;
    a0 = fmaf(__expf(lreluf(av.x + ad0) - mx0) * rd0, xr[c], a0);
    a1 = fmaf(__expf(lreluf(av.y + ad1) - mx1) * rd1, xr[c + 16], a1);
    a2 = fmaf(__expf(lreluf(av.z + ad2) - mx2) * rd2, xr[c + 32], a2);
    a3 = fmaf(__expf(lreluf(av.w + ad3) - mx3) * rd3, xr[c + 48], a3);
  }
  a0 += __shfl_xor(a0, 16); a0 += __shfl_xor(a0, 32);
  a1 += __shfl_xor(a1, 16); a1 += __shfl_xor(a1, 32);
  a2 += __shfl_xor(a2, 16); a2 += __shfl_xor(a2, 32);
  a3 += __shfl_xor(a3, 16); a3 += __shfl_xor(a3, 32);
  float v = (g == 0) ? a0 : ((g == 1) ? a1 : ((g == 2) ? a2 : a3));
  int col = c + 16 * g;
  v += p.gat_bias[cell * 64 + col];
  unsigned short hi = f2bf(v);
  size_t o = (size_t)cell * 1280000 + (size_t)node * 64 + col;
  p.spH[o] = hi;
  p.spL[o] = f2bf(v - bf2f(hi));
}

// ---- mix core ----
__device__ void mix_core(const P& p, int rb, int t, int lane, const float* hldsw) {
  const int l15 = lane & 15, lg = lane >> 4;
  const int m0 = rb * 16;
  const int gm = m0 + l15;
  const unsigned short* hHs_[3] = { p.hH, p.hH + 1280000, p.hH + 2560000 };
  const unsigned short* hLs_[3] = { p.hL, p.hL + 1280000, p.hL + 2560000 };
  bf16x8 aH[3][2], aL[3][2];
#pragma unroll
  for (int ch = 0; ch < 2; ++ch) {
    if (hldsw) {
      bf16x8 th, tl;
#pragma unroll
      for (int i = 0; i < 8; ++i) {
        float v = hldsw[l15 * 68 + ch * 32 + lg * 8 + i];
        unsigned short hi = f2bf(v);
        th[i] = (short)hi;
        tl[i] = (short)f2bf(v - bf2f(hi));
      }
      aH[0][ch] = th; aL[0][ch] = tl;
    } else {
      size_t off = (size_t)gm * 64 + ch * 32 + lg * 8;
      aH[0][ch] = *reinterpret_cast<const bf16x8*>(hHs_[0] + off);
      aL[0][ch] = *reinterpret_cast<const bf16x8*>(hLs_[0] + off);
    }
    size_t off = (size_t)gm * 64 + ch * 32 + lg * 8;
    aH[1][ch] = *reinterpret_cast<const bf16x8*>(hHs_[1] + off);
    aL[1][ch] = *reinterpret_cast<const bf16x8*>(hLs_[1] + off);
    aH[2][ch] = *reinterpret_cast<const bf16x8*>(hHs_[2] + off);
    aL[2][ch] = *reinterpret_cast<const bf16x8*>(hLs_[2] + off);
  }
  f32x4 acc[6];
#pragma unroll
  for (int nf = 0; nf < 6; ++nf) acc[nf] = (f32x4){0.f, 0.f, 0.f, 0.f};
#pragma unroll
  for (int nf = 0; nf < 6; ++nf) {
#pragma unroll
    for (int s = 0; s < 3; ++s) {
#pragma unroll
      for (int ch = 0; ch < 2; ++ch) {
        size_t wo = (size_t)(nf * 16 + l15) * 192 + s * 64 + ch * 32 + lg * 8;
        bf16x8 bH = *reinterpret_cast<const bf16x8*>(p.w1H + wo);
        bf16x8 bL = *reinterpret_cast<const bf16x8*>(p.w1L + wo);
        acc[nf] = mfma16(aH[s][ch], bH, acc[nf]);
        acc[nf] = mfma16(aH[s][ch], bL, acc[nf]);
        acc[nf] = mfma16(aL[s][ch], bH, acc[nf]);
      }
    }
  }
#pragma unroll
  for (int r = 0; r < 4; ++r) {
    float p0 = 0.f, p1 = 0.f, p2 = 0.f;
#pragma unroll
    for (int nf = 0; nf < 6; ++nf) {
      int n = nf * 16 + l15;
      float hdv = fmaxf(acc[nf][r] + p.b1[n], 0.f);
      p0 = fmaf(hdv, p.w2[n], p0);
      p1 = fmaf(hdv, p.w2[96 + n], p1);
      p2 = fmaf(hdv, p.w2[192 + n], p2);
    }
#pragma unroll
    for (int off = 1; off < 16; off <<= 1) {
      p0 += __shfl_xor(p0, off); p1 += __shfl_xor(p1, off); p2 += __shfl_xor(p2, off);
    }
    float q0 = p0 + p.b2[0], q1 = p1 + p.b2[1], q2 = p2 + p.b2[2];
    float mx = fmaxf(q0, fmaxf(q1, q2));
    float e0 = __expf(q0 - mx), e1 = __expf(q1 - mx), e2 = __expf(q2 - mx);
    float rs = 1.0f / (e0 + e1 + e2);
    float w0 = e0 * rs, w1v = e1 * rs, w2v = e2 * rs;
    int row = m0 + lg * 4 + r;
    size_t ob = ((size_t)row * TT + t) * 64;
    size_t hb = (size_t)row * 64;
#pragma unroll
    for (int q = 0; q < 4; ++q) {
      int col = l15 + 16 * q;
      float vf = hldsw ? hldsw[(lg * 4 + r) * 68 + col]
                       : (bf2f(hHs_[0][hb + col]) + bf2f(hLs_[0][hb + col]));
      float vm = bf2f(hHs_[1][hb + col]) + bf2f(hLs_[1][hb + col]);
      float vs = bf2f(hHs_[2][hb + col]) + bf2f(hLs_[2][hb + col]);
      p.out[ob + col] = w0 * vf + w1v * vm + w2v * vs;
    }
  }
}

// ---- phase C: gates GEMM + LSTM pointwise + LayerNorm (+ fused mix) ----
__device__ void phaseC(const P& p, int cell, int rb, int t, bool fused, int lane, float* hldsw) {
  const int l15 = lane & 15, lg = lane >> 4;
  const int m0 = rb * 16;
  const int gm = m0 + l15;
  size_t cs = (size_t)cell * 1280000;
  const unsigned short* spH = p.spH + cs;
  const unsigned short* spL = p.spL + cs;
  unsigned short* hH = p.hH + cs;
  unsigned short* hL = p.hL + cs;
  const unsigned short* WihH = p.wihH + cell * 16384;
  const unsigned short* WihL = p.wihL + cell * 16384;
  const unsigned short* WhhH = p.whhH + cell * 16384;
  const unsigned short* WhhL = p.whhL + cell * 16384;
  const float* bsum = p.bsum + cell * 256;
  float* cst = p.c_st + cs;
  const float* g_ln = p.ln_g + cell * 64;
  const float* b_ln = p.ln_b + cell * 64;

  bf16x8 sHa[2], sLa[2], hHa[2], hLa[2];
#pragma unroll
  for (int ch = 0; ch < 2; ++ch) {
    size_t off = (size_t)gm * 64 + ch * 32 + lg * 8;
    sHa[ch] = *reinterpret_cast<const bf16x8*>(spH + off);
    sLa[ch] = *reinterpret_cast<const bf16x8*>(spL + off);
    hHa[ch] = *reinterpret_cast<const bf16x8*>(hH + off);
    hLa[ch] = *reinterpret_cast<const bf16x8*>(hL + off);
  }
  f32x4 acc[16];
#pragma unroll
  for (int nf = 0; nf < 16; ++nf) acc[nf] = (f32x4){0.f, 0.f, 0.f, 0.f};
#pragma unroll
  for (int nf = 0; nf < 16; ++nf) {
#pragma unroll
    for (int ch = 0; ch < 2; ++ch) {
      size_t wo = (size_t)(nf * 16 + l15) * 64 + ch * 32 + lg * 8;
      bf16x8 bH = *reinterpret_cast<const bf16x8*>(WihH + wo);
      bf16x8 bL = *reinterpret_cast<const bf16x8*>(WihL + wo);
      acc[nf] = mfma16(sHa[ch], bH, acc[nf]);
      acc[nf] = mfma16(sHa[ch], bL, acc[nf]);
      acc[nf] = mfma16(sLa[ch], bH, acc[nf]);
      bf16x8 cH = *reinterpret_cast<const bf16x8*>(WhhH + wo);
      bf16x8 cL = *reinterpret_cast<const bf16x8*>(WhhL + wo);
      acc[nf] = mfma16(hHa[ch], cH, acc[nf]);
      acc[nf] = mfma16(hHa[ch], cL, acc[nf]);
      acc[nf] = mfma16(hLa[ch], cH, acc[nf]);
    }
  }
  float hn[4][4], cn[4][4];
#pragma unroll
  for (int cq = 0; cq < 4; ++cq) {
    int col = cq * 16 + l15;
    float bi = bsum[col], bff = bsum[64 + col], bg = bsum[128 + col], bo = bsum[192 + col];
#pragma unroll
    for (int r = 0; r < 4; ++r) {
      int row = m0 + lg * 4 + r;
      float gi = acc[cq][r] + bi;
      float gf = acc[cq + 4][r] + bff;
      float gg = acc[cq + 8][r] + bg;
      float go = acc[cq + 12][r] + bo;
      float cold = cst[(size_t)row * 64 + col];
      float cv = sigf(gf) * cold + sigf(gi) * tanhf(gg);
      cn[cq][r] = cv;
      hn[cq][r] = sigf(go) * tanhf(cv);
    }
  }
#pragma unroll
  for (int r = 0; r < 4; ++r) {
    float s = hn[0][r] + hn[1][r] + hn[2][r] + hn[3][r];
#pragma unroll
    for (int off = 1; off < 16; off <<= 1) s += __shfl_xor(s, off);
    float mu = s * (1.0f / 64.0f);
    float vv = 0.f;
#pragma unroll
    for (int cq = 0; cq < 4; ++cq) { float d = hn[cq][r] - mu; vv += d * d; }
#pragma unroll
    for (int off = 1; off < 16; off <<= 1) vv += __shfl_xor(vv, off);
    float rstd = rsqrtf(vv * (1.0f / 64.0f) + 1e-5f);
    int row = m0 + lg * 4 + r;
#pragma unroll
    for (int cq = 0; cq < 4; ++cq) {
      int col = cq * 16 + l15;
      float hl = (hn[cq][r] - mu) * rstd * g_ln[col] + b_ln[col];
      unsigned short hi = f2bf(hl);
      hH[(size_t)row * 64 + col] = hi;
      hL[(size_t)row * 64 + col] = f2bf(hl - bf2f(hi));
      cst[(size_t)row * 64 + col] = cn[cq][r];
      if (fused) hldsw[(lg * 4 + r) * 68 + col] = hl;
    }
  }
  if (fused) mix_core(p, rb, t, lane, hldsw);
}

// ---- the mega kernel ----
__global__ __launch_bounds__(256, 4) void mega(P p) {
  const int tid = threadIdx.x;
  const int lane = tid & 63, wv = tid >> 6;
  const int wid = blockIdx.x * 4 + wv;
  const int gtid = blockIdx.x * 256 + tid;
  __shared__ float hlds[4][16][68];
  float* hldsw = &hlds[wv][0][0];

  // ---- S0: zero state + counters; convert weights ----
  for (int i = gtid; i < 3840000; i += NTHREADS) p.c_st[i] = 0.f;
  unsigned int* hz = (unsigned int*)p.hH;
  for (int i = gtid; i < 3840000; i += NTHREADS) hz[i] = 0u;
  for (int i = gtid; i < NNODES + 8; i += NTHREADS) { p.deg[i] = 0; p.cnt[i] = 0; }
  for (int i = gtid; i < 49152; i += NTHREADS) {
    if (i < 12288) { float w = p.lin_w[i]; unsigned short h = f2bf(w); p.linH[i] = h; p.linL[i] = f2bf(w - bf2f(h)); }
    { float w = p.w_ih[i]; unsigned short h = f2bf(w); p.wihH[i] = h; p.wihL[i] = f2bf(w - bf2f(h)); }
    { float w = p.w_hh[i]; unsigned short h = f2bf(w); p.whhH[i] = h; p.whhL[i] = f2bf(w - bf2f(h)); }
    if (i < 18432) { float w = p.w1[i]; unsigned short h = f2bf(w); p.w1H[i] = h; p.w1L[i] = f2bf(w - bf2f(h)); }
    if (i < 768) p.bsum[i] = p.b_ih[i] + p.b_hh[i];
  }
  gbar(p);

  // ---- S1: degree count ----
  for (int e = gtid; e < EB; e += NTHREADS) {
    int dst;
    if (e < BE) { int r = e % EE; int b = e / EE; dst = p.eidx[EE + r] + b * NPER; }
    else dst = e - BE;
    atomicAdd(&p.deg[dst], 1);
  }
  gbar(p);

  // ---- S2: per-block chunk sums (CHUNK nodes per block) ----
  if (wv == 0) {
    int n = blockIdx.x * CHUNK + lane;
    int v = (lane < CHUNK && n < NNODES) ? p.deg[n] : 0;
#pragma unroll
    for (int off = 1; off < 64; off <<= 1) v += __shfl_xor(v, off);
    if (lane == 0) p.csum[blockIdx.x] = v;
  }
  gbar(p);

  // ---- S3: block 0 scans NB chunk sums ----
  if (blockIdx.x == 0 && wv == 0) {
    int s[16]; int tot = 0;
#pragma unroll
    for (int j = 0; j < 16; ++j) { s[j] = p.csum[lane * 16 + j]; tot += s[j]; }
    int inc = tot;
#pragma unroll
    for (int off = 1; off < 64; off <<= 1) { int u = __shfl_up(inc, off); if (lane >= off) inc += u; }
    int excl = inc - tot;
#pragma unroll
    for (int j = 0; j < 16; ++j) { p.cbase[lane * 16 + j] = excl; excl += s[j]; }
  }
  gbar(p);

  // ---- S4: per-block startp fill ----
  if (tid == 0) {
    int base_ = p.cbase[blockIdx.x];
    for (int i2 = 0; i2 < CHUNK; ++i2) {
      int n = blockIdx.x * CHUNK + i2;
      if (n <= NNODES) { p.startp[n] = base_; if (n < NNODES) base_ += p.deg[n]; }
    }
  }
  gbar(p);

  // ---- S5: fill adjacency + A(t=0, all 3 cells) ----
  for (int e = gtid; e < EB; e += NTHREADS) {
    int src, dst;
    if (e < BE) { int r = e % EE; int b = e / EE; src = p.eidx[r] + b * NPER; dst = p.eidx[EE + r] + b * NPER; }
    else { src = e - BE; dst = src; }
    int pos = atomicAdd(&p.cnt[dst], 1);
    p.adj[p.startp[dst] + pos] = src;
  }
  for (int task = wid; task < 3 * 1250; task += NW)
    phaseA(p, task / 1250, task % 1250, 0, lane);
  gbar(p);

  // ---- main time loop ----
  for (int t = 0; t < TT; ++t) {
    const int ncell = (t == 0) ? 3 : ((t == 15) ? 2 : 1);
    const int nA = (t < TT - 1) ? (((t + 1) == 15) ? 2 : 1) * 1250 : 0;

    for (int task = wid; task < ncell * NNODES; task += NW)
      phaseB(p, task / NNODES, task % NNODES, lane);
    gbar(p);

    if (ncell == 1) {
      const int tot = 1250 + nA;
      for (int task = wid; task < tot; task += NW) {
        if (task < 1250) phaseC(p, 0, task, t, true, lane, hldsw);
        else { int idx = task - 1250; phaseA(p, idx / 1250, idx % 1250, t + 1, lane); }
      }
      gbar(p);
    } else {
      for (int task = wid; task < ncell * 1250; task += NW)
        phaseC(p, task / 1250, task % 1250, t, false, lane, hldsw);
      gbar(p);
      const int tot = 1250 + nA;
      for (int task = wid; task < tot; task += NW) {
        if (task < 1250) mix_core(p, task, t, lane, nullptr);
        else { int idx = task - 1250; phaseA(p, idx / 1250, idx % 1250, t + 1, lane); }
      }
      gbar(p);
    }
  }
}

// ---- host side ----
extern "C" void kernel_launch(void* const* d_in, const int* in_sizes, int n_in,
                              void* d_out, int out_size, void* d_ws, size_t ws_size,
                              hipStream_t stream) {
  P p;
  p.x_seq    = (const float*)d_in[0];
  p.lin_w    = (const float*)d_in[1];
  p.att_src  = (const float*)d_in[2];
  p.att_dst  = (const float*)d_in[3];
  p.gat_bias = (const float*)d_in[4];
  p.w_ih     = (const float*)d_in[5];
  p.w_hh     = (const float*)d_in[6];
  p.b_ih     = (const float*)d_in[7];
  p.b_hh     = (const float*)d_in[8];
  p.ln_g     = (const float*)d_in[9];
  p.ln_b     = (const float*)d_in[10];
  p.w1       = (const float*)d_in[11];
  p.b1       = (const float*)d_in[12];
  p.w2       = (const float*)d_in[13];
  p.b2       = (const float*)d_in[14];
  p.eidx     = (const int*)d_in[15];
  p.out      = (float*)d_out;

  char* base = (char*)d_ws;
  size_t off = 0;
  auto alloc = [&](size_t bytes) { char* r = base + off; off += (bytes + 255) & ~(size_t)255; return r; };
  p.c_st  = (float*)alloc(3840000 * 4);
  p.hH    = (unsigned short*)alloc(7680000 * 2);
  p.hL    = p.hH + 3840000;
  p.xt    = (float*)alloc(3840000 * 4);
  p.spH   = (unsigned short*)alloc(3840000 * 2);
  p.spL   = (unsigned short*)alloc(3840000 * 2);
  p.asrc  = (float*)alloc(240000 * 4);
  p.adst  = (float*)alloc(240000 * 4);
  p.bsum  = (float*)alloc(768 * 4);
  p.linH  = (unsigned short*)alloc(12288 * 2);
  p.linL  = (unsigned short*)alloc(12288 * 2);
  p.wihH  = (unsigned short*)alloc(49152 * 2);
  p.wihL  = (unsigned short*)alloc(49152 * 2);
  p.whhH  = (unsigned short*)alloc(49152 * 2);
  p.whhL  = (unsigned short*)alloc(49152 * 2);
  p.w1H   = (unsigned short*)alloc(18432 * 2);
  p.w1L   = (unsigned short*)alloc(18432 * 2);
  p.deg   = (int*)alloc(20008 * 4);
  p.cnt   = (int*)alloc(20008 * 4);
  p.startp= (int*)alloc(20008 * 4);
  p.adj   = (int*)alloc(340000 * 4);
  p.csum  = (int*)alloc(NB * 4);
  p.cbase = (int*)alloc(NB * 4);
  int* barzone = (int*)alloc(8192);
  p.bar_grp = barzone;              // 16 groups * 64-int stride
  p.bar_top = barzone + NGRP * 64;
  p.bar_gen = barzone + NGRP * 64 + 16;

  hipMemsetAsync(barzone, 0, 8192, stream);
  mega<<<NB, 256, 0, stream>>>(p);
}

// Round 6
// 3022.058 us; speedup vs baseline: 3.7383x; 1.3832x over previous
//
#include <hip/hip_runtime.h>
#include <cstddef>

#define TT 16
#define NNODES 20000
#define EE 80000
#define BE 320000
#define EB 340000
#define NPER 5000
#define NB 768
#define NTHREADS (NB * 256)
#define NWAVES (NB * 4)
#define NGRP 16
#define GSZ (NB / NGRP)
#define SL 384   // task slots per XCD-pair (192 blocks * 2)

typedef __attribute__((ext_vector_type(8))) short bf16x8;
typedef __attribute__((ext_vector_type(4))) float f32x4;

__device__ __forceinline__ float sigf(float x) { return 1.0f / (1.0f + __expf(-x)); }
__device__ __forceinline__ float lreluf(float x) { return x > 0.0f ? x : 0.2f * x; }

__device__ __forceinline__ unsigned short f2bf(float x) {
  union { float f; unsigned u; } v; v.f = x;
  unsigned r = v.u + 0x7FFF + ((v.u >> 16) & 1);
  return (unsigned short)(r >> 16);
}
__device__ __forceinline__ float bf2f(unsigned short u) {
  union { unsigned u; float f; } v; v.u = ((unsigned)u) << 16; return v.f;
}
__device__ __forceinline__ f32x4 mfma16(bf16x8 a, bf16x8 b, f32x4 c) {
  return __builtin_amdgcn_mfma_f32_16x16x32_bf16(a, b, c, 0, 0, 0);
}
// split 8 consecutive f32 into hi/lo bf16 fragments
__device__ __forceinline__ void split8(const float* s, bf16x8& th, bf16x8& tl) {
#pragma unroll
  for (int i = 0; i < 8; ++i) {
    float v = s[i];
    unsigned short h = f2bf(v);
    th[i] = (short)h;
    tl[i] = (short)f2bf(v - bf2f(h));
  }
}

struct P {
  const float *x_seq, *att_src, *att_dst, *gat_bias, *ln_g, *ln_b, *b1, *w2, *b2;
  const float *lin_w, *w_ih, *w_hh, *b_ih, *b_hh, *w1;
  const int* eidx;
  float* out;
  float *xt, *asrc, *adst, *bsum, *cstg;
  unsigned short *hHg, *hLg;
  unsigned short *linH, *linL, *wihH, *wihL, *whhH, *whhL, *w1H, *w1L;
  int *deg, *cnt, *startp, *adj;
  int *bar_grp, *bar_top, *bar_gen;
};

// ---- grid barrier: tree arrival, relaxed spin, single acquire fence on exit ----
__device__ __forceinline__ void gbar(const P& p) {
  __syncthreads();
  if (threadIdx.x == 0) {
    int g = __hip_atomic_load(p.bar_gen, __ATOMIC_RELAXED, __HIP_MEMORY_SCOPE_AGENT);
    int* gc = p.bar_grp + (blockIdx.x & (NGRP - 1)) * 64;
    int v = __hip_atomic_fetch_add(gc, 1, __ATOMIC_ACQ_REL, __HIP_MEMORY_SCOPE_AGENT);
    bool done = false;
    if (v == GSZ - 1) {
      __hip_atomic_store(gc, 0, __ATOMIC_RELAXED, __HIP_MEMORY_SCOPE_AGENT);
      int w = __hip_atomic_fetch_add(p.bar_top, 1, __ATOMIC_ACQ_REL, __HIP_MEMORY_SCOPE_AGENT);
      if (w == NGRP - 1) {
        __hip_atomic_store(p.bar_top, 0, __ATOMIC_RELAXED, __HIP_MEMORY_SCOPE_AGENT);
        __hip_atomic_store(p.bar_gen, g + 1, __ATOMIC_RELEASE, __HIP_MEMORY_SCOPE_AGENT);
        done = true;
      }
    }
    if (!done) {
      while (__hip_atomic_load(p.bar_gen, __ATOMIC_RELAXED, __HIP_MEMORY_SCOPE_AGENT) == g)
        __builtin_amdgcn_s_sleep(2);
      __builtin_amdgcn_fence(__ATOMIC_ACQUIRE, "agent");
    }
  }
  __syncthreads();
}

// ---- phase A: xt GEMM (split bf16) + GAT attention coefficients; parity buffers ----
__device__ void phaseA(const P& p, int cell, int rb, int tstep, int lane) {
  const int l15 = lane & 15, lg = lane >> 4;
  const int m0 = rb * 16;
  const int par = tstep & 1;
  const float* A = p.x_seq + (size_t)tstep * 1280000;
  const unsigned short* WH = p.linH + cell * 4096;
  const unsigned short* WL = p.linL + cell * 4096;
  float* xtC = p.xt + (size_t)(cell * 2 + par) * 1280000;
  float* asC = p.asrc + (size_t)(cell * 2 + par) * 80000;
  float* adC = p.adst + (size_t)(cell * 2 + par) * 80000;
  const float* attS = p.att_src + cell * 64;
  const float* attD = p.att_dst + cell * 64;

  const float* arow = A + (size_t)(m0 + l15) * 64;
  bf16x8 aH[2], aL[2];
#pragma unroll
  for (int ch = 0; ch < 2; ++ch) {
    float4 u0 = *reinterpret_cast<const float4*>(arow + ch * 32 + lg * 8);
    float4 u1 = *reinterpret_cast<const float4*>(arow + ch * 32 + lg * 8 + 4);
    float v[8] = {u0.x, u0.y, u0.z, u0.w, u1.x, u1.y, u1.z, u1.w};
    bf16x8 th, tl;
#pragma unroll
    for (int i = 0; i < 8; ++i) {
      unsigned short hi = f2bf(v[i]);
      th[i] = (short)hi;
      tl[i] = (short)f2bf(v[i] - bf2f(hi));
    }
    aH[ch] = th; aL[ch] = tl;
  }
  f32x4 acc[4];
#pragma unroll
  for (int nf = 0; nf < 4; ++nf) acc[nf] = (f32x4){0.f, 0.f, 0.f, 0.f};
#pragma unroll
  for (int nf = 0; nf < 4; ++nf) {
#pragma unroll
    for (int ch = 0; ch < 2; ++ch) {
      size_t wo = (size_t)(nf * 16 + l15) * 64 + ch * 32 + lg * 8;
      bf16x8 bH = *reinterpret_cast<const bf16x8*>(WH + wo);
      bf16x8 bL = *reinterpret_cast<const bf16x8*>(WL + wo);
      acc[nf] = mfma16(aH[ch], bH, acc[nf]);
      acc[nf] = mfma16(aH[ch], bL, acc[nf]);
      acc[nf] = mfma16(aL[ch], bH, acc[nf]);
    }
  }
#pragma unroll
  for (int nf = 0; nf < 4; ++nf) {
    float sv = attS[nf * 16 + l15], dv = attD[nf * 16 + l15];
#pragma unroll
    for (int r = 0; r < 4; ++r) {
      int row = m0 + lg * 4 + r;
      float v = acc[nf][r];
      float ps = v * sv, pd = v * dv;
#pragma unroll
      for (int off = 1; off < 16; off <<= 1) { ps += __shfl_xor(ps, off); pd += __shfl_xor(pd, off); }
      xtC[(size_t)row * 64 + nf * 16 + l15] = v;
      if (l15 == 0) { asC[row * 4 + nf] = ps; adC[row * 4 + nf] = pd; }
    }
  }
}

// ---- gather one node (full wave), result row into LDS ----
__device__ void gather_node(const P& p, int cell, int tstep, int node, int lane, float* sprow) {
  const int par = tstep & 1;
  const float* asr = p.asrc + (size_t)(cell * 2 + par) * 80000;
  const float* xtC = p.xt + (size_t)(cell * 2 + par) * 1280000;
  const float* adC = p.adst + (size_t)(cell * 2 + par) * 80000;
  int s0 = p.startp[node];
  int dg = p.startp[node + 1] - s0;
  float4 adv = *reinterpret_cast<const float4*>(adC + (size_t)node * 4);
  float ad0 = adv.x, ad1 = adv.y, ad2 = adv.z, ad3 = adv.w;

  float mx0 = -1e30f, mx1 = -1e30f, mx2 = -1e30f, mx3 = -1e30f;
  for (int e = lane; e < dg; e += 64) {
    int src = p.adj[s0 + e];
    float4 av = *reinterpret_cast<const float4*>(asr + (size_t)src * 4);
    mx0 = fmaxf(mx0, lreluf(av.x + ad0));
    mx1 = fmaxf(mx1, lreluf(av.y + ad1));
    mx2 = fmaxf(mx2, lreluf(av.z + ad2));
    mx3 = fmaxf(mx3, lreluf(av.w + ad3));
  }
#pragma unroll
  for (int off = 1; off < 64; off <<= 1) {
    mx0 = fmaxf(mx0, __shfl_xor(mx0, off));
    mx1 = fmaxf(mx1, __shfl_xor(mx1, off));
    mx2 = fmaxf(mx2, __shfl_xor(mx2, off));
    mx3 = fmaxf(mx3, __shfl_xor(mx3, off));
  }
  float dn0 = 0.f, dn1 = 0.f, dn2 = 0.f, dn3 = 0.f;
  for (int e = lane; e < dg; e += 64) {
    int src = p.adj[s0 + e];
    float4 av = *reinterpret_cast<const float4*>(asr + (size_t)src * 4);
    dn0 += __expf(lreluf(av.x + ad0) - mx0);
    dn1 += __expf(lreluf(av.y + ad1) - mx1);
    dn2 += __expf(lreluf(av.z + ad2) - mx2);
    dn3 += __expf(lreluf(av.w + ad3) - mx3);
  }
#pragma unroll
  for (int off = 1; off < 64; off <<= 1) {
    dn0 += __shfl_xor(dn0, off);
    dn1 += __shfl_xor(dn1, off);
    dn2 += __shfl_xor(dn2, off);
    dn3 += __shfl_xor(dn3, off);
  }
  float rd0 = 1.0f / (dn0 + 1e-16f), rd1 = 1.0f / (dn1 + 1e-16f);
  float rd2 = 1.0f / (dn2 + 1e-16f), rd3 = 1.0f / (dn3 + 1e-16f);

  const int g = lane >> 4, c = lane & 15, head = c >> 2;
  float mxh = head == 0 ? mx0 : head == 1 ? mx1 : head == 2 ? mx2 : mx3;
  float adh = head == 0 ? ad0 : head == 1 ? ad1 : head == 2 ? ad2 : ad3;
  float rdh = head == 0 ? rd0 : head == 1 ? rd1 : head == 2 ? rd2 : rd3;
  float a0 = 0.f, a1 = 0.f, a2 = 0.f, a3 = 0.f;
  for (int e = g; e < dg; e += 4) {
    int src = p.adj[s0 + e];
    float av = asr[(size_t)src * 4 + head];
    float al = __expf(lreluf(av + adh) - mxh) * rdh;
    float4 xv = *reinterpret_cast<const float4*>(xtC + (size_t)src * 64 + c * 4);
    a0 = fmaf(al, xv.x, a0);
    a1 = fmaf(al, xv.y, a1);
    a2 = fmaf(al, xv.z, a2);
    a3 = fmaf(al, xv.w, a3);
  }
  a0 += __shfl_xor(a0, 16); a0 += __shfl_xor(a0, 32);
  a1 += __shfl_xor(a1, 16); a1 += __shfl_xor(a1, 32);
  a2 += __shfl_xor(a2, 16); a2 += __shfl_xor(a2, 32);
  a3 += __shfl_xor(a3, 16); a3 += __shfl_xor(a3, 32);
  if (g == 0) {
    float4 bz = *reinterpret_cast<const float4*>(p.gat_bias + cell * 64 + c * 4);
    *reinterpret_cast<float4*>(sprow + c * 4) = make_float4(a0 + bz.x, a1 + bz.y, a2 + bz.z, a3 + bz.w);
  }
}

// ---- mix: [hf(LDS f32)|hm(hi)|hs(hi)] @ w1^T -> relu -> w2 -> softmax3 -> blend ----
__device__ void mixcore(const P& p, int rb, int t, int lane, const float* hf) {
  const int l15 = lane & 15, lg = lane >> 4;
  const int m0 = rb * 16;
  bf16x8 aH0[2], aL0[2], aH1[2], aH2[2];
#pragma unroll
  for (int ch = 0; ch < 2; ++ch) {
    split8(hf + l15 * 68 + ch * 32 + lg * 8, aH0[ch], aL0[ch]);
    size_t off = (size_t)(m0 + l15) * 64 + ch * 32 + lg * 8;
    aH1[ch] = *reinterpret_cast<const bf16x8*>(p.hHg + off);
    aH2[ch] = *reinterpret_cast<const bf16x8*>(p.hHg + 1280000 + off);
  }
  f32x4 acc[6];
#pragma unroll
  for (int nf = 0; nf < 6; ++nf) acc[nf] = (f32x4){0.f, 0.f, 0.f, 0.f};
#pragma unroll
  for (int nf = 0; nf < 6; ++nf) {
#pragma unroll
    for (int ch = 0; ch < 2; ++ch) {
      size_t wo = (size_t)(nf * 16 + l15) * 192 + ch * 32 + lg * 8;
      bf16x8 bH = *reinterpret_cast<const bf16x8*>(p.w1H + wo);
      bf16x8 bL = *reinterpret_cast<const bf16x8*>(p.w1L + wo);
      acc[nf] = mfma16(aH0[ch], bH, acc[nf]);
      acc[nf] = mfma16(aH0[ch], bL, acc[nf]);
      acc[nf] = mfma16(aL0[ch], bH, acc[nf]);
      bH = *reinterpret_cast<const bf16x8*>(p.w1H + wo + 64);
      bL = *reinterpret_cast<const bf16x8*>(p.w1L + wo + 64);
      acc[nf] = mfma16(aH1[ch], bH, acc[nf]);
      acc[nf] = mfma16(aH1[ch], bL, acc[nf]);
      bH = *reinterpret_cast<const bf16x8*>(p.w1H + wo + 128);
      bL = *reinterpret_cast<const bf16x8*>(p.w1L + wo + 128);
      acc[nf] = mfma16(aH2[ch], bH, acc[nf]);
      acc[nf] = mfma16(aH2[ch], bL, acc[nf]);
    }
  }
#pragma unroll
  for (int r = 0; r < 4; ++r) {
    float p0 = 0.f, p1 = 0.f, p2 = 0.f;
#pragma unroll
    for (int nf = 0; nf < 6; ++nf) {
      int n = nf * 16 + l15;
      float hdv = fmaxf(acc[nf][r] + p.b1[n], 0.f);
      p0 = fmaf(hdv, p.w2[n], p0);
      p1 = fmaf(hdv, p.w2[96 + n], p1);
      p2 = fmaf(hdv, p.w2[192 + n], p2);
    }
#pragma unroll
    for (int off = 1; off < 16; off <<= 1) {
      p0 += __shfl_xor(p0, off); p1 += __shfl_xor(p1, off); p2 += __shfl_xor(p2, off);
    }
    float q0 = p0 + p.b2[0], q1 = p1 + p.b2[1], q2 = p2 + p.b2[2];
    float mx = fmaxf(q0, fmaxf(q1, q2));
    float e0 = __expf(q0 - mx), e1 = __expf(q1 - mx), e2 = __expf(q2 - mx);
    float rs = 1.0f / (e0 + e1 + e2);
    float w0 = e0 * rs, w1v = e1 * rs, w2v = e2 * rs;
    int row = m0 + lg * 4 + r;
    size_t ob = ((size_t)row * TT + t) * 64;
    size_t hb = (size_t)row * 64;
#pragma unroll
    for (int q = 0; q < 4; ++q) {
      int col = l15 + 16 * q;
      float vf = hf[(lg * 4 + r) * 68 + col];
      float vm = bf2f(p.hHg[hb + col]);
      float vs = bf2f(p.hHg[1280000 + hb + col]);
      p.out[ob + col] = w0 * vf + w1v * vm + w2v * vs;
    }
  }
}

// ---- fast cell C: sp(LDS f32) + h(LDS f32) + c(regs) -> LSTM -> LN -> h(LDS) ----
__device__ void phaseC_fast(const P& p, int rb, int t, bool domix, int lane,
                            const float* sp, float* hf, float creg[4][4]) {
  const int l15 = lane & 15, lg = lane >> 4;
  bf16x8 sH[2], sL[2], hHa[2], hLa[2];
#pragma unroll
  for (int ch = 0; ch < 2; ++ch) {
    split8(sp + l15 * 68 + ch * 32 + lg * 8, sH[ch], sL[ch]);
    split8(hf + l15 * 68 + ch * 32 + lg * 8, hHa[ch], hLa[ch]);
  }
  f32x4 acc[16];
#pragma unroll
  for (int nf = 0; nf < 16; ++nf) acc[nf] = (f32x4){0.f, 0.f, 0.f, 0.f};
#pragma unroll
  for (int nf = 0; nf < 16; ++nf) {
#pragma unroll
    for (int ch = 0; ch < 2; ++ch) {
      size_t wo = (size_t)(nf * 16 + l15) * 64 + ch * 32 + lg * 8;
      bf16x8 bH = *reinterpret_cast<const bf16x8*>(p.wihH + wo);
      bf16x8 bL = *reinterpret_cast<const bf16x8*>(p.wihL + wo);
      acc[nf] = mfma16(sH[ch], bH, acc[nf]);
      acc[nf] = mfma16(sH[ch], bL, acc[nf]);
      acc[nf] = mfma16(sL[ch], bH, acc[nf]);
      bf16x8 cH = *reinterpret_cast<const bf16x8*>(p.whhH + wo);
      bf16x8 cL = *reinterpret_cast<const bf16x8*>(p.whhL + wo);
      acc[nf] = mfma16(hHa[ch], cH, acc[nf]);
      acc[nf] = mfma16(hHa[ch], cL, acc[nf]);
      acc[nf] = mfma16(hLa[ch], cH, acc[nf]);
    }
  }
  float hn[4][4];
#pragma unroll
  for (int cq = 0; cq < 4; ++cq) {
    int col = cq * 16 + l15;
    float bi = p.bsum[col], bff = p.bsum[64 + col], bg = p.bsum[128 + col], bo = p.bsum[192 + col];
#pragma unroll
    for (int r = 0; r < 4; ++r) {
      float gi = acc[cq][r] + bi;
      float gf = acc[cq + 4][r] + bff;
      float gg = acc[cq + 8][r] + bg;
      float go = acc[cq + 12][r] + bo;
      float cv = sigf(gf) * creg[cq][r] + sigf(gi) * tanhf(gg);
      creg[cq][r] = cv;
      hn[cq][r] = sigf(go) * tanhf(cv);
    }
  }
#pragma unroll
  for (int r = 0; r < 4; ++r) {
    float s = hn[0][r] + hn[1][r] + hn[2][r] + hn[3][r];
#pragma unroll
    for (int off = 1; off < 16; off <<= 1) s += __shfl_xor(s, off);
    float mu = s * (1.0f / 64.0f);
    float vv = 0.f;
#pragma unroll
    for (int cq = 0; cq < 4; ++cq) { float d = hn[cq][r] - mu; vv += d * d; }
#pragma unroll
    for (int off = 1; off < 16; off <<= 1) vv += __shfl_xor(vv, off);
    float rstd = rsqrtf(vv * (1.0f / 64.0f) + 1e-5f);
#pragma unroll
    for (int cq = 0; cq < 4; ++cq) {
      int col = cq * 16 + l15;
      hf[(lg * 4 + r) * 68 + col] = (hn[cq][r] - mu) * rstd * p.ln_g[col] + p.ln_b[col];
    }
  }
  if (domix) mixcore(p, rb, t, lane, hf);
}

// ---- med/slow C: sp(LDS) + global h/c planes ----
__device__ void phaseC_glob(const P& p, int cell, int rb, int lane, const float* sp) {
  const int l15 = lane & 15, lg = lane >> 4;
  const int m0 = rb * 16;
  const int ci = cell - 1;
  unsigned short* hH = p.hHg + (size_t)ci * 1280000;
  unsigned short* hL = p.hLg + (size_t)ci * 1280000;
  float* cst = p.cstg + (size_t)ci * 1280000;
  const unsigned short* WihH = p.wihH + cell * 16384;
  const unsigned short* WihL = p.wihL + cell * 16384;
  const unsigned short* WhhH = p.whhH + cell * 16384;
  const unsigned short* WhhL = p.whhL + cell * 16384;
  const float* bsum = p.bsum + cell * 256;
  const float* g_ln = p.ln_g + cell * 64;
  const float* b_ln = p.ln_b + cell * 64;

  bf16x8 sH[2], sL[2], hHa[2], hLa[2];
#pragma unroll
  for (int ch = 0; ch < 2; ++ch) {
    split8(sp + l15 * 68 + ch * 32 + lg * 8, sH[ch], sL[ch]);
    size_t off = (size_t)(m0 + l15) * 64 + ch * 32 + lg * 8;
    hHa[ch] = *reinterpret_cast<const bf16x8*>(hH + off);
    hLa[ch] = *reinterpret_cast<const bf16x8*>(hL + off);
  }
  f32x4 acc[16];
#pragma unroll
  for (int nf = 0; nf < 16; ++nf) acc[nf] = (f32x4){0.f, 0.f, 0.f, 0.f};
#pragma unroll
  for (int nf = 0; nf < 16; ++nf) {
#pragma unroll
    for (int ch = 0; ch < 2; ++ch) {
      size_t wo = (size_t)(nf * 16 + l15) * 64 + ch * 32 + lg * 8;
      bf16x8 bH = *reinterpret_cast<const bf16x8*>(WihH + wo);
      bf16x8 bL = *reinterpret_cast<const bf16x8*>(WihL + wo);
      acc[nf] = mfma16(sH[ch], bH, acc[nf]);
      acc[nf] = mfma16(sH[ch], bL, acc[nf]);
      acc[nf] = mfma16(sL[ch], bH, acc[nf]);
      bf16x8 cH = *reinterpret_cast<const bf16x8*>(WhhH + wo);
      bf16x8 cL = *reinterpret_cast<const bf16x8*>(WhhL + wo);
      acc[nf] = mfma16(hHa[ch], cH, acc[nf]);
      acc[nf] = mfma16(hHa[ch], cL, acc[nf]);
      acc[nf] = mfma16(hLa[ch], cH, acc[nf]);
    }
  }
  float hn[4][4], cn[4][4];
#pragma unroll
  for (int cq = 0; cq < 4; ++cq) {
    int col = cq * 16 + l15;
    float bi = bsum[col], bff = bsum[64 + col], bg = bsum[128 + col], bo = bsum[192 + col];
#pragma unroll
    for (int r = 0; r < 4; ++r) {
      int row = m0 + lg * 4 + r;
      float gi = acc[cq][r] + bi;
      float gf = acc[cq + 4][r] + bff;
      float gg = acc[cq + 8][r] + bg;
      float go = acc[cq + 12][r] + bo;
      float cv = sigf(gf) * cst[(size_t)row * 64 + col] + sigf(gi) * tanhf(gg);
      cn[cq][r] = cv;
      hn[cq][r] = sigf(go) * tanhf(cv);
    }
  }
#pragma unroll
  for (int r = 0; r < 4; ++r) {
    float s = hn[0][r] + hn[1][r] + hn[2][r] + hn[3][r];
#pragma unroll
    for (int off = 1; off < 16; off <<= 1) s += __shfl_xor(s, off);
    float mu = s * (1.0f / 64.0f);
    float vv = 0.f;
#pragma unroll
    for (int cq = 0; cq < 4; ++cq) { float d = hn[cq][r] - mu; vv += d * d; }
#pragma unroll
    for (int off = 1; off < 16; off <<= 1) vv += __shfl_xor(vv, off);
    float rstd = rsqrtf(vv * (1.0f / 64.0f) + 1e-5f);
    int row = m0 + lg * 4 + r;
#pragma unroll
    for (int cq = 0; cq < 4; ++cq) {
      int col = cq * 16 + l15;
      float hl = (hn[cq][r] - mu) * rstd * g_ln[col] + b_ln[col];
      unsigned short hi = f2bf(hl);
      hH[(size_t)row * 64 + col] = hi;
      hL[(size_t)row * 64 + col] = f2bf(hl - bf2f(hi));
      cst[(size_t)row * 64 + col] = cn[cq][r];
    }
  }
}

// ---- the mega kernel ----
__global__ __launch_bounds__(256, 3) void mega(P p) {
  const int tid = threadIdx.x, b = blockIdx.x;
  const int lane = tid & 63, wv = tid >> 6;
  const int gwid = b * 4 + wv, gtid = b * 256 + tid;
  __shared__ float sp_lds[4][16][68];
  __shared__ float hf_lds[2][16][68];

  const int pair = (b & 7) >> 1;
  const int pb = (b >> 3) * 2 + (b & 1);
  const int slot = pb * 2 + (wv >> 1);
  const int b0 = (pair * 1250 + 3) >> 2;
  const int cf = (((pair + 1) * 1250 + 3) >> 2) - b0;

  for (int i = tid; i < 2 * 16 * 68; i += 256) ((float*)hf_lds)[i] = 0.f;
  float creg[4][4];
#pragma unroll
  for (int a = 0; a < 4; ++a)
#pragma unroll
    for (int r = 0; r < 4; ++r) creg[a][r] = 0.f;

  // S0: zero med/slow state + counters; split weights
  for (int i = gtid; i < 2560000; i += NTHREADS) p.cstg[i] = 0.f;
  unsigned int* hz = (unsigned int*)p.hHg;   // hHg(2)+hLg(2) contiguous: 5.12M u16
  for (int i = gtid; i < 2560000; i += NTHREADS) hz[i] = 0u;
  for (int i = gtid; i < NNODES + 8; i += NTHREADS) { p.deg[i] = 0; p.cnt[i] = 0; }
  for (int i = gtid; i < 49152; i += NTHREADS) {
    if (i < 12288) { float w = p.lin_w[i]; unsigned short h = f2bf(w); p.linH[i] = h; p.linL[i] = f2bf(w - bf2f(h)); }
    { float w = p.w_ih[i]; unsigned short h = f2bf(w); p.wihH[i] = h; p.wihL[i] = f2bf(w - bf2f(h)); }
    { float w = p.w_hh[i]; unsigned short h = f2bf(w); p.whhH[i] = h; p.whhL[i] = f2bf(w - bf2f(h)); }
    if (i < 18432) { float w = p.w1[i]; unsigned short h = f2bf(w); p.w1H[i] = h; p.w1L[i] = f2bf(w - bf2f(h)); }
    if (i < 768) p.bsum[i] = p.b_ih[i] + p.b_hh[i];
  }
  gbar(p);

  // S1: degree count
  for (int e = gtid; e < EB; e += NTHREADS) {
    int dst;
    if (e < BE) { int r = e % EE; int bb = e / EE; dst = p.eidx[EE + r] + bb * NPER; }
    else dst = e - BE;
    atomicAdd(&p.deg[dst], 1);
  }
  gbar(p);

  // S2: scan in block 0 (256 threads x 79 nodes)
  if (b == 0) {
    int* ib = (int*)&sp_lds[0][0][0];
    int s = 0;
    for (int j = 0; j < 79; ++j) {
      int n = tid * 79 + j;
      if (n < NNODES) s += p.deg[n];
    }
    ib[tid] = s;
    __syncthreads();
    for (int off = 1; off < 256; off <<= 1) {
      int tv = (tid >= off) ? ib[tid - off] : 0;
      __syncthreads();
      ib[tid] += tv;
      __syncthreads();
    }
    int excl = ib[tid] - s;
    for (int j = 0; j < 79; ++j) {
      int n = tid * 79 + j;
      if (n < NNODES) { p.startp[n] = excl; excl += p.deg[n]; }
    }
    if (tid == 255) p.startp[NNODES] = ib[255];
  }
  gbar(p);

  // S3: fill adjacency + A(t=0) for all 3 cells
  for (int e = gtid; e < EB; e += NTHREADS) {
    int src, dst;
    if (e < BE) { int r = e % EE; int bb = e / EE; src = p.eidx[r] + bb * NPER; dst = p.eidx[EE + r] + bb * NPER; }
    else { src = e - BE; dst = src; }
    int pos = atomicAdd(&p.cnt[dst], 1);
    p.adj[p.startp[dst] + pos] = src;
  }
  for (int idx = gwid; idx < 3750; idx += NWAVES)
    phaseA(p, idx / 1250, idx % 1250, 0, lane);
  gbar(p);

  // ---- main time loop ----
  for (int t = 0; t < TT; ++t) {
    const bool multi = (t == 0) || (t == 15);
    const int totv = cf * ((t == 0) ? 3 : ((t == 15) ? 2 : 1));
    int nIter = (totv - pb * 2 + SL - 1) / SL;
    if (pb * 2 >= totv) nIter = 0;

    for (int k = 0; k < nIter; ++k) {
      int v = slot + k * SL;
      bool act = v < totv;
      int cell = 0, rb = 0;
      if (act) {
        cell = (v >= cf) + (v >= 2 * cf);
        rb = b0 + v - cell * cf;
        float* sprow0 = &sp_lds[wv >> 1][(wv & 1) * 8][0];
        int nb0 = rb * 16 + (wv & 1) * 8;
        for (int j = 0; j < 8; ++j)
          gather_node(p, cell, t, nb0 + j, lane, sprow0 + j * 68);
      }
      __syncthreads();
      if (act && (wv & 1) == 0) {
        if (cell == 0)
          phaseC_fast(p, rb, t, !multi, lane, &sp_lds[wv >> 1][0][0], &hf_lds[wv >> 1][0][0], creg);
        else
          phaseC_glob(p, cell, rb, lane, &sp_lds[wv >> 1][0][0]);
      }
      __syncthreads();
    }
    // A(t+1) on w1/w3 (fast tiles; + med tiles when t+1==15)
    if ((wv & 1) == 1 && t < TT - 1) {
      int cntA = cf * (((t + 1) == 15) ? 2 : 1);
      for (int vA = slot; vA < cntA; vA += SL) {
        int cellA = (vA >= cf) ? 1 : 0;
        phaseA(p, cellA, b0 + (vA - cellA * cf), t + 1, lane);
      }
    }
    gbar(p);
    if (multi) {
      if ((wv & 1) == 0 && slot < cf)
        mixcore(p, b0 + slot, t, lane, &hf_lds[wv >> 1][0][0]);
      gbar(p);
    }
  }
}

// ---- host side ----
extern "C" void kernel_launch(void* const* d_in, const int* in_sizes, int n_in,
                              void* d_out, int out_size, void* d_ws, size_t ws_size,
                              hipStream_t stream) {
  P p;
  p.x_seq    = (const float*)d_in[0];
  p.lin_w    = (const float*)d_in[1];
  p.att_src  = (const float*)d_in[2];
  p.att_dst  = (const float*)d_in[3];
  p.gat_bias = (const float*)d_in[4];
  p.w_ih     = (const float*)d_in[5];
  p.w_hh     = (const float*)d_in[6];
  p.b_ih     = (const float*)d_in[7];
  p.b_hh     = (const float*)d_in[8];
  p.ln_g     = (const float*)d_in[9];
  p.ln_b     = (const float*)d_in[10];
  p.w1       = (const float*)d_in[11];
  p.b1       = (const float*)d_in[12];
  p.w2       = (const float*)d_in[13];
  p.b2       = (const float*)d_in[14];
  p.eidx     = (const int*)d_in[15];
  p.out      = (float*)d_out;

  char* base = (char*)d_ws;
  size_t off = 0;
  auto alloc = [&](size_t bytes) { char* r = base + off; off += (bytes + 255) & ~(size_t)255; return r; };
  p.xt    = (float*)alloc((size_t)6 * 1280000 * 4);        // [cell][parity]
  p.asrc  = (float*)alloc((size_t)6 * 80000 * 4);
  p.adst  = (float*)alloc((size_t)6 * 80000 * 4);
  p.hHg   = (unsigned short*)alloc((size_t)4 * 1280000 * 2); // hHg[2] + hLg[2] contiguous
  p.hLg   = p.hHg + 2 * 1280000;
  p.cstg  = (float*)alloc((size_t)2 * 1280000 * 4);
  p.bsum  = (float*)alloc(768 * 4);
  p.linH  = (unsigned short*)alloc(12288 * 2);
  p.linL  = (unsigned short*)alloc(12288 * 2);
  p.wihH  = (unsigned short*)alloc(49152 * 2);
  p.wihL  = (unsigned short*)alloc(49152 * 2);
  p.whhH  = (unsigned short*)alloc(49152 * 2);
  p.whhL  = (unsigned short*)alloc(49152 * 2);
  p.w1H   = (unsigned short*)alloc(18432 * 2);
  p.w1L   = (unsigned short*)alloc(18432 * 2);
  p.deg   = (int*)alloc(20008 * 4);
  p.cnt   = (int*)alloc(20008 * 4);
  p.startp= (int*)alloc(20008 * 4);
  p.adj   = (int*)alloc(340000 * 4);
  int* barzone = (int*)alloc(8192);
  p.bar_grp = barzone;
  p.bar_top = barzone + NGRP * 64;
  p.bar_gen = barzone + NGRP * 64 + 16;

  hipMemsetAsync(barzone, 0, 8192, stream);
  mega<<<NB, 256, 0, stream>>>(p);
}

// Round 7
// 2865.795 us; speedup vs baseline: 3.9422x; 1.0545x over previous
//
#include <hip/hip_runtime.h>
#include <cstddef>

#define TT 16
#define NNODES 20000
#define EE 80000
#define BE 320000
#define EB 340000
#define NPER 5000
#define NB 768
#define NTHREADS (NB * 256)
#define NWAVES (NB * 4)
#define NGRP 16
#define GSZ (NB / NGRP)
#define SL 384   // task slots per XCD-pair (192 blocks * 2 wave-pairs)

typedef __attribute__((ext_vector_type(8))) short bf16x8;
typedef __attribute__((ext_vector_type(4))) float f32x4;

__device__ __forceinline__ float sigf(float x) { return 1.0f / (1.0f + __expf(-x)); }
__device__ __forceinline__ float lreluf(float x) { return x > 0.0f ? x : 0.2f * x; }

__device__ __forceinline__ unsigned short f2bf(float x) {
  union { float f; unsigned u; } v; v.f = x;
  unsigned r = v.u + 0x7FFF + ((v.u >> 16) & 1);
  return (unsigned short)(r >> 16);
}
__device__ __forceinline__ float bf2f(unsigned short u) {
  union { unsigned u; float f; } v; v.u = ((unsigned)u) << 16; return v.f;
}
__device__ __forceinline__ unsigned short f2h(float x) {
  _Float16 h = (_Float16)x;
  return __builtin_bit_cast(unsigned short, h);
}
__device__ __forceinline__ float h2f(unsigned short u) {
  return (float)__builtin_bit_cast(_Float16, u);
}
__device__ __forceinline__ f32x4 mfma16(bf16x8 a, bf16x8 b, f32x4 c) {
  return __builtin_amdgcn_mfma_f32_16x16x32_bf16(a, b, c, 0, 0, 0);
}
// split 8 consecutive f32 into hi/lo bf16 fragments
__device__ __forceinline__ void split8(const float* s, bf16x8& th, bf16x8& tl) {
#pragma unroll
  for (int i = 0; i < 8; ++i) {
    float v = s[i];
    unsigned short h = f2bf(v);
    th[i] = (short)h;
    tl[i] = (short)f2bf(v - bf2f(h));
  }
}

struct P {
  const float *x_seq, *att_src, *att_dst, *gat_bias, *ln_g, *ln_b, *b1, *w2, *b2;
  const float *lin_w, *w_ih, *w_hh, *b_ih, *b_hh, *w1;
  const int* eidx;
  float* out;
  float *asrc, *adst, *bsum, *cstg;
  unsigned short *xt16;
  unsigned short *hHg, *hLg;
  unsigned short *linH, *linL, *wihH, *wihL, *whhH, *whhL, *w1H, *w1L;
  int *deg, *cnt, *startp, *adj;
  int *bar_grp, *bar_top, *bar_gen;
};

// ---- grid barrier: tree arrival, relaxed spin, single acquire fence on exit ----
__device__ __forceinline__ void gbar(const P& p) {
  __syncthreads();
  if (threadIdx.x == 0) {
    int g = __hip_atomic_load(p.bar_gen, __ATOMIC_RELAXED, __HIP_MEMORY_SCOPE_AGENT);
    int* gc = p.bar_grp + (blockIdx.x & (NGRP - 1)) * 64;
    int v = __hip_atomic_fetch_add(gc, 1, __ATOMIC_ACQ_REL, __HIP_MEMORY_SCOPE_AGENT);
    bool done = false;
    if (v == GSZ - 1) {
      __hip_atomic_store(gc, 0, __ATOMIC_RELAXED, __HIP_MEMORY_SCOPE_AGENT);
      int w = __hip_atomic_fetch_add(p.bar_top, 1, __ATOMIC_ACQ_REL, __HIP_MEMORY_SCOPE_AGENT);
      if (w == NGRP - 1) {
        __hip_atomic_store(p.bar_top, 0, __ATOMIC_RELAXED, __HIP_MEMORY_SCOPE_AGENT);
        __hip_atomic_store(p.bar_gen, g + 1, __ATOMIC_RELEASE, __HIP_MEMORY_SCOPE_AGENT);
        done = true;
      }
    }
    if (!done) {
      while (__hip_atomic_load(p.bar_gen, __ATOMIC_RELAXED, __HIP_MEMORY_SCOPE_AGENT) == g)
        __builtin_amdgcn_s_sleep(2);
      __builtin_amdgcn_fence(__ATOMIC_ACQUIRE, "agent");
    }
  }
  __syncthreads();
}

// ---- phase A: xt GEMM (split bf16) + GAT attention coefficients; parity buffers ----
__device__ void phaseA(const P& p, int cell, int rb, int tstep, int lane) {
  const int l15 = lane & 15, lg = lane >> 4;
  const int m0 = rb * 16;
  const int par = tstep & 1;
  const float* A = p.x_seq + (size_t)tstep * 1280000;
  const unsigned short* WH = p.linH + cell * 4096;
  const unsigned short* WL = p.linL + cell * 4096;
  unsigned short* xtC = p.xt16 + (size_t)(cell * 2 + par) * 1280000;
  float* asC = p.asrc + (size_t)(cell * 2 + par) * 80000;
  float* adC = p.adst + (size_t)(cell * 2 + par) * 80000;
  const float* attS = p.att_src + cell * 64;
  const float* attD = p.att_dst + cell * 64;

  const float* arow = A + (size_t)(m0 + l15) * 64;
  bf16x8 aH[2], aL[2];
#pragma unroll
  for (int ch = 0; ch < 2; ++ch) {
    float4 u0 = *reinterpret_cast<const float4*>(arow + ch * 32 + lg * 8);
    float4 u1 = *reinterpret_cast<const float4*>(arow + ch * 32 + lg * 8 + 4);
    float v[8] = {u0.x, u0.y, u0.z, u0.w, u1.x, u1.y, u1.z, u1.w};
    bf16x8 th, tl;
#pragma unroll
    for (int i = 0; i < 8; ++i) {
      unsigned short hi = f2bf(v[i]);
      th[i] = (short)hi;
      tl[i] = (short)f2bf(v[i] - bf2f(hi));
    }
    aH[ch] = th; aL[ch] = tl;
  }
  f32x4 acc[4];
#pragma unroll
  for (int nf = 0; nf < 4; ++nf) acc[nf] = (f32x4){0.f, 0.f, 0.f, 0.f};
#pragma unroll
  for (int nf = 0; nf < 4; ++nf) {
#pragma unroll
    for (int ch = 0; ch < 2; ++ch) {
      size_t wo = (size_t)(nf * 16 + l15) * 64 + ch * 32 + lg * 8;
      bf16x8 bH = *reinterpret_cast<const bf16x8*>(WH + wo);
      bf16x8 bL = *reinterpret_cast<const bf16x8*>(WL + wo);
      acc[nf] = mfma16(aH[ch], bH, acc[nf]);
      acc[nf] = mfma16(aH[ch], bL, acc[nf]);
      acc[nf] = mfma16(aL[ch], bH, acc[nf]);
    }
  }
#pragma unroll
  for (int nf = 0; nf < 4; ++nf) {
    float sv = attS[nf * 16 + l15], dv = attD[nf * 16 + l15];
#pragma unroll
    for (int r = 0; r < 4; ++r) {
      int row = m0 + lg * 4 + r;
      float v = acc[nf][r];
      float ps = v * sv, pd = v * dv;
#pragma unroll
      for (int off = 1; off < 16; off <<= 1) { ps += __shfl_xor(ps, off); pd += __shfl_xor(pd, off); }
      xtC[(size_t)row * 64 + nf * 16 + l15] = f2h(v);
      if (l15 == 0) { asC[row * 4 + nf] = ps; adC[row * 4 + nf] = pd; }
    }
  }
}

// ---- gather one node: single-pass softmax (no max-subtract; logits bounded),
//      alpha+src staged in LDS, f16 xt PV ----
__device__ void gather_node(const P& p, int cell, int tstep, int node, int lane,
                            float* sprow, float* alds, int* slds) {
  const int par = tstep & 1;
  const float* asr = p.asrc + (size_t)(cell * 2 + par) * 80000;
  const unsigned short* xtC = p.xt16 + (size_t)(cell * 2 + par) * 1280000;
  const float* adC = p.adst + (size_t)(cell * 2 + par) * 80000;
  int s0 = p.startp[node];
  int dg = p.startp[node + 1] - s0;
  float4 adv = *reinterpret_cast<const float4*>(adC + (size_t)node * 4);

  float ex0 = 0.f, ex1 = 0.f, ex2 = 0.f, ex3 = 0.f;
  int src0 = 0;
  if (lane < dg) {
    src0 = p.adj[s0 + lane];
    float4 av = *reinterpret_cast<const float4*>(asr + (size_t)src0 * 4);
    ex0 = __expf(lreluf(av.x + adv.x));
    ex1 = __expf(lreluf(av.y + adv.y));
    ex2 = __expf(lreluf(av.z + adv.z));
    ex3 = __expf(lreluf(av.w + adv.w));
  }
  float dn0 = ex0, dn1 = ex1, dn2 = ex2, dn3 = ex3;
  for (int e = 64 + lane; e < dg; e += 64) {   // rare tail
    int src = p.adj[s0 + e];
    float4 av = *reinterpret_cast<const float4*>(asr + (size_t)src * 4);
    dn0 += __expf(lreluf(av.x + adv.x));
    dn1 += __expf(lreluf(av.y + adv.y));
    dn2 += __expf(lreluf(av.z + adv.z));
    dn3 += __expf(lreluf(av.w + adv.w));
  }
#pragma unroll
  for (int off = 1; off < 64; off <<= 1) {
    dn0 += __shfl_xor(dn0, off);
    dn1 += __shfl_xor(dn1, off);
    dn2 += __shfl_xor(dn2, off);
    dn3 += __shfl_xor(dn3, off);
  }
  float rd0 = 1.0f / (dn0 + 1e-16f), rd1 = 1.0f / (dn1 + 1e-16f);
  float rd2 = 1.0f / (dn2 + 1e-16f), rd3 = 1.0f / (dn3 + 1e-16f);
  if (lane < dg) {
    *reinterpret_cast<float4*>(alds + lane * 4) =
        make_float4(ex0 * rd0, ex1 * rd1, ex2 * rd2, ex3 * rd3);
    slds[lane] = src0;
  }

  const int g = lane >> 4, c = lane & 15, head = c >> 2;
  float a0 = 0.f, a1 = 0.f, a2 = 0.f, a3 = 0.f;
  int dglim = dg < 64 ? dg : 64;
  for (int e = g; e < dglim; e += 4) {
    float alpha = alds[e * 4 + head];      // 16-lane broadcast
    int src = slds[e];
    ushort4 xv = *reinterpret_cast<const ushort4*>(xtC + (size_t)src * 64 + c * 4);
    a0 = fmaf(alpha, h2f(xv.x), a0);
    a1 = fmaf(alpha, h2f(xv.y), a1);
    a2 = fmaf(alpha, h2f(xv.z), a2);
    a3 = fmaf(alpha, h2f(xv.w), a3);
  }
  if (dg > 64) {                            // rare tail: recompute alpha
    float rdh = head == 0 ? rd0 : head == 1 ? rd1 : head == 2 ? rd2 : rd3;
    float adh = head == 0 ? adv.x : head == 1 ? adv.y : head == 2 ? adv.z : adv.w;
    for (int e = 64 + g; e < dg; e += 4) {
      int src = p.adj[s0 + e];
      float av = asr[(size_t)src * 4 + head];
      float alpha = __expf(lreluf(av + adh)) * rdh;
      ushort4 xv = *reinterpret_cast<const ushort4*>(xtC + (size_t)src * 64 + c * 4);
      a0 = fmaf(alpha, h2f(xv.x), a0);
      a1 = fmaf(alpha, h2f(xv.y), a1);
      a2 = fmaf(alpha, h2f(xv.z), a2);
      a3 = fmaf(alpha, h2f(xv.w), a3);
    }
  }
  a0 += __shfl_xor(a0, 16); a0 += __shfl_xor(a0, 32);
  a1 += __shfl_xor(a1, 16); a1 += __shfl_xor(a1, 32);
  a2 += __shfl_xor(a2, 16); a2 += __shfl_xor(a2, 32);
  a3 += __shfl_xor(a3, 16); a3 += __shfl_xor(a3, 32);
  if (g == 0) {
    float4 bz = *reinterpret_cast<const float4*>(p.gat_bias + cell * 64 + c * 4);
    *reinterpret_cast<float4*>(sprow + c * 4) = make_float4(a0 + bz.x, a1 + bz.y, a2 + bz.z, a3 + bz.w);
  }
}

// ---- mix: [hf(LDS f32)|hm(hi)|hs(hi)] @ w1^T -> relu -> w2 -> softmax3 -> blend ----
__device__ void mixcore(const P& p, int rb, int t, int lane, const float* hf) {
  const int l15 = lane & 15, lg = lane >> 4;
  const int m0 = rb * 16;
  bf16x8 aH0[2], aL0[2], aH1[2], aH2[2];
#pragma unroll
  for (int ch = 0; ch < 2; ++ch) {
    split8(hf + l15 * 68 + ch * 32 + lg * 8, aH0[ch], aL0[ch]);
    size_t off = (size_t)(m0 + l15) * 64 + ch * 32 + lg * 8;
    aH1[ch] = *reinterpret_cast<const bf16x8*>(p.hHg + off);
    aH2[ch] = *reinterpret_cast<const bf16x8*>(p.hHg + 1280000 + off);
  }
  f32x4 acc[6];
#pragma unroll
  for (int nf = 0; nf < 6; ++nf) acc[nf] = (f32x4){0.f, 0.f, 0.f, 0.f};
#pragma unroll
  for (int nf = 0; nf < 6; ++nf) {
#pragma unroll
    for (int ch = 0; ch < 2; ++ch) {
      size_t wo = (size_t)(nf * 16 + l15) * 192 + ch * 32 + lg * 8;
      bf16x8 bH = *reinterpret_cast<const bf16x8*>(p.w1H + wo);
      bf16x8 bL = *reinterpret_cast<const bf16x8*>(p.w1L + wo);
      acc[nf] = mfma16(aH0[ch], bH, acc[nf]);
      acc[nf] = mfma16(aH0[ch], bL, acc[nf]);
      acc[nf] = mfma16(aL0[ch], bH, acc[nf]);
      bH = *reinterpret_cast<const bf16x8*>(p.w1H + wo + 64);
      bL = *reinterpret_cast<const bf16x8*>(p.w1L + wo + 64);
      acc[nf] = mfma16(aH1[ch], bH, acc[nf]);
      acc[nf] = mfma16(aH1[ch], bL, acc[nf]);
      bH = *reinterpret_cast<const bf16x8*>(p.w1H + wo + 128);
      bL = *reinterpret_cast<const bf16x8*>(p.w1L + wo + 128);
      acc[nf] = mfma16(aH2[ch], bH, acc[nf]);
      acc[nf] = mfma16(aH2[ch], bL, acc[nf]);
    }
  }
#pragma unroll
  for (int r = 0; r < 4; ++r) {
    float p0 = 0.f, p1 = 0.f, p2 = 0.f;
#pragma unroll
    for (int nf = 0; nf < 6; ++nf) {
      int n = nf * 16 + l15;
      float hdv = fmaxf(acc[nf][r] + p.b1[n], 0.f);
      p0 = fmaf(hdv, p.w2[n], p0);
      p1 = fmaf(hdv, p.w2[96 + n], p1);
      p2 = fmaf(hdv, p.w2[192 + n], p2);
    }
#pragma unroll
    for (int off = 1; off < 16; off <<= 1) {
      p0 += __shfl_xor(p0, off); p1 += __shfl_xor(p1, off); p2 += __shfl_xor(p2, off);
    }
    float q0 = p0 + p.b2[0], q1 = p1 + p.b2[1], q2 = p2 + p.b2[2];
    float mx = fmaxf(q0, fmaxf(q1, q2));
    float e0 = __expf(q0 - mx), e1 = __expf(q1 - mx), e2 = __expf(q2 - mx);
    float rs = 1.0f / (e0 + e1 + e2);
    float w0 = e0 * rs, w1v = e1 * rs, w2v = e2 * rs;
    int row = m0 + lg * 4 + r;
    size_t ob = ((size_t)row * TT + t) * 64;
    size_t hb = (size_t)row * 64;
#pragma unroll
    for (int q = 0; q < 4; ++q) {
      int col = l15 + 16 * q;
      float vf = hf[(lg * 4 + r) * 68 + col];
      float vm = bf2f(p.hHg[hb + col]);
      float vs = bf2f(p.hHg[1280000 + hb + col]);
      p.out[ob + col] = w0 * vf + w1v * vm + w2v * vs;
    }
  }
}

// ---- fast cell C: sp(LDS f32) + h(LDS f32) + c(regs) -> LSTM -> LN -> h(LDS) ----
__device__ void phaseC_fast(const P& p, int rb, int t, bool domix, int lane,
                            const float* sp, float* hf, float creg[4][4]) {
  const int l15 = lane & 15, lg = lane >> 4;
  bf16x8 sH[2], sL[2], hHa[2], hLa[2];
#pragma unroll
  for (int ch = 0; ch < 2; ++ch) {
    split8(sp + l15 * 68 + ch * 32 + lg * 8, sH[ch], sL[ch]);
    split8(hf + l15 * 68 + ch * 32 + lg * 8, hHa[ch], hLa[ch]);
  }
  f32x4 acc[16];
#pragma unroll
  for (int nf = 0; nf < 16; ++nf) acc[nf] = (f32x4){0.f, 0.f, 0.f, 0.f};
#pragma unroll
  for (int nf = 0; nf < 16; ++nf) {
#pragma unroll
    for (int ch = 0; ch < 2; ++ch) {
      size_t wo = (size_t)(nf * 16 + l15) * 64 + ch * 32 + lg * 8;
      bf16x8 bH = *reinterpret_cast<const bf16x8*>(p.wihH + wo);
      bf16x8 bL = *reinterpret_cast<const bf16x8*>(p.wihL + wo);
      acc[nf] = mfma16(sH[ch], bH, acc[nf]);
      acc[nf] = mfma16(sH[ch], bL, acc[nf]);
      acc[nf] = mfma16(sL[ch], bH, acc[nf]);
      bf16x8 cH = *reinterpret_cast<const bf16x8*>(p.whhH + wo);
      bf16x8 cL = *reinterpret_cast<const bf16x8*>(p.whhL + wo);
      acc[nf] = mfma16(hHa[ch], cH, acc[nf]);
      acc[nf] = mfma16(hHa[ch], cL, acc[nf]);
      acc[nf] = mfma16(hLa[ch], cH, acc[nf]);
    }
  }
  float hn[4][4];
#pragma unroll
  for (int cq = 0; cq < 4; ++cq) {
    int col = cq * 16 + l15;
    float bi = p.bsum[col], bff = p.bsum[64 + col], bg = p.bsum[128 + col], bo = p.bsum[192 + col];
#pragma unroll
    for (int r = 0; r < 4; ++r) {
      float gi = acc[cq][r] + bi;
      float gf = acc[cq + 4][r] + bff;
      float gg = acc[cq + 8][r] + bg;
      float go = acc[cq + 12][r] + bo;
      float cv = sigf(gf) * creg[cq][r] + sigf(gi) * tanhf(gg);
      creg[cq][r] = cv;
      hn[cq][r] = sigf(go) * tanhf(cv);
    }
  }
#pragma unroll
  for (int r = 0; r < 4; ++r) {
    float s = hn[0][r] + hn[1][r] + hn[2][r] + hn[3][r];
#pragma unroll
    for (int off = 1; off < 16; off <<= 1) s += __shfl_xor(s, off);
    float mu = s * (1.0f / 64.0f);
    float vv = 0.f;
#pragma unroll
    for (int cq = 0; cq < 4; ++cq) { float d = hn[cq][r] - mu; vv += d * d; }
#pragma unroll
    for (int off = 1; off < 16; off <<= 1) vv += __shfl_xor(vv, off);
    float rstd = rsqrtf(vv * (1.0f / 64.0f) + 1e-5f);
#pragma unroll
    for (int cq = 0; cq < 4; ++cq) {
      int col = cq * 16 + l15;
      hf[(lg * 4 + r) * 68 + col] = (hn[cq][r] - mu) * rstd * p.ln_g[col] + p.ln_b[col];
    }
  }
  if (domix) mixcore(p, rb, t, lane, hf);
}

// ---- med/slow C: sp(LDS) + global h/c planes ----
__device__ void phaseC_glob(const P& p, int cell, int rb, int lane, const float* sp) {
  const int l15 = lane & 15, lg = lane >> 4;
  const int m0 = rb * 16;
  const int ci = cell - 1;
  unsigned short* hH = p.hHg + (size_t)ci * 1280000;
  unsigned short* hL = p.hLg + (size_t)ci * 1280000;
  float* cst = p.cstg + (size_t)ci * 1280000;
  const unsigned short* WihH = p.wihH + cell * 16384;
  const unsigned short* WihL = p.wihL + cell * 16384;
  const unsigned short* WhhH = p.whhH + cell * 16384;
  const unsigned short* WhhL = p.whhL + cell * 16384;
  const float* bsum = p.bsum + cell * 256;
  const float* g_ln = p.ln_g + cell * 64;
  const float* b_ln = p.ln_b + cell * 64;

  bf16x8 sH[2], sL[2], hHa[2], hLa[2];
#pragma unroll
  for (int ch = 0; ch < 2; ++ch) {
    split8(sp + l15 * 68 + ch * 32 + lg * 8, sH[ch], sL[ch]);
    size_t off = (size_t)(m0 + l15) * 64 + ch * 32 + lg * 8;
    hHa[ch] = *reinterpret_cast<const bf16x8*>(hH + off);
    hLa[ch] = *reinterpret_cast<const bf16x8*>(hL + off);
  }
  f32x4 acc[16];
#pragma unroll
  for (int nf = 0; nf < 16; ++nf) acc[nf] = (f32x4){0.f, 0.f, 0.f, 0.f};
#pragma unroll
  for (int nf = 0; nf < 16; ++nf) {
#pragma unroll
    for (int ch = 0; ch < 2; ++ch) {
      size_t wo = (size_t)(nf * 16 + l15) * 64 + ch * 32 + lg * 8;
      bf16x8 bH = *reinterpret_cast<const bf16x8*>(WihH + wo);
      bf16x8 bL = *reinterpret_cast<const bf16x8*>(WihL + wo);
      acc[nf] = mfma16(sH[ch], bH, acc[nf]);
      acc[nf] = mfma16(sH[ch], bL, acc[nf]);
      acc[nf] = mfma16(sL[ch], bH, acc[nf]);
      bf16x8 cH = *reinterpret_cast<const bf16x8*>(WhhH + wo);
      bf16x8 cL = *reinterpret_cast<const bf16x8*>(WhhL + wo);
      acc[nf] = mfma16(hHa[ch], cH, acc[nf]);
      acc[nf] = mfma16(hHa[ch], cL, acc[nf]);
      acc[nf] = mfma16(hLa[ch], cH, acc[nf]);
    }
  }
  float hn[4][4], cn[4][4];
#pragma unroll
  for (int cq = 0; cq < 4; ++cq) {
    int col = cq * 16 + l15;
    float bi = bsum[col], bff = bsum[64 + col], bg = bsum[128 + col], bo = bsum[192 + col];
#pragma unroll
    for (int r = 0; r < 4; ++r) {
      int row = m0 + lg * 4 + r;
      float gi = acc[cq][r] + bi;
      float gf = acc[cq + 4][r] + bff;
      float gg = acc[cq + 8][r] + bg;
      float go = acc[cq + 12][r] + bo;
      float cv = sigf(gf) * cst[(size_t)row * 64 + col] + sigf(gi) * tanhf(gg);
      cn[cq][r] = cv;
      hn[cq][r] = sigf(go) * tanhf(cv);
    }
  }
#pragma unroll
  for (int r = 0; r < 4; ++r) {
    float s = hn[0][r] + hn[1][r] + hn[2][r] + hn[3][r];
#pragma unroll
    for (int off = 1; off < 16; off <<= 1) s += __shfl_xor(s, off);
    float mu = s * (1.0f / 64.0f);
    float vv = 0.f;
#pragma unroll
    for (int cq = 0; cq < 4; ++cq) { float d = hn[cq][r] - mu; vv += d * d; }
#pragma unroll
    for (int off = 1; off < 16; off <<= 1) vv += __shfl_xor(vv, off);
    float rstd = rsqrtf(vv * (1.0f / 64.0f) + 1e-5f);
    int row = m0 + lg * 4 + r;
#pragma unroll
    for (int cq = 0; cq < 4; ++cq) {
      int col = cq * 16 + l15;
      float hl = (hn[cq][r] - mu) * rstd * g_ln[col] + b_ln[col];
      unsigned short hi = f2bf(hl);
      hH[(size_t)row * 64 + col] = hi;
      hL[(size_t)row * 64 + col] = f2bf(hl - bf2f(hi));
      cst[(size_t)row * 64 + col] = cn[cq][r];
    }
  }
}

// ---- the mega kernel ----
__global__ __launch_bounds__(256, 3) void mega(P p) {
  const int tid = threadIdx.x, b = blockIdx.x;
  const int lane = tid & 63, wv = tid >> 6;
  const int gwid = b * 4 + wv, gtid = b * 256 + tid;
  __shared__ float sp_lds[4][16][68];
  __shared__ float hf_lds[2][16][68];
  __shared__ float al_lds[4][256];
  __shared__ int   sr_lds[4][64];

  const int pair = (b & 7) >> 1;
  const int pb = (b >> 3) * 2 + (b & 1);
  const int slot = pb * 2 + (wv >> 1);
  const int b0 = (pair * 1250 + 3) >> 2;
  const int cf = (((pair + 1) * 1250 + 3) >> 2) - b0;

  for (int i = tid; i < 2 * 16 * 68; i += 256) ((float*)hf_lds)[i] = 0.f;
  float creg[4][4];
#pragma unroll
  for (int a = 0; a < 4; ++a)
#pragma unroll
    for (int r = 0; r < 4; ++r) creg[a][r] = 0.f;

  // S0: zero med/slow state + counters; split weights
  for (int i = gtid; i < 2560000; i += NTHREADS) p.cstg[i] = 0.f;
  unsigned int* hz = (unsigned int*)p.hHg;   // hHg(2)+hLg(2) contiguous: 5.12M u16
  for (int i = gtid; i < 2560000; i += NTHREADS) hz[i] = 0u;
  for (int i = gtid; i < NNODES + 8; i += NTHREADS) { p.deg[i] = 0; p.cnt[i] = 0; }
  for (int i = gtid; i < 49152; i += NTHREADS) {
    if (i < 12288) { float w = p.lin_w[i]; unsigned short h = f2bf(w); p.linH[i] = h; p.linL[i] = f2bf(w - bf2f(h)); }
    { float w = p.w_ih[i]; unsigned short h = f2bf(w); p.wihH[i] = h; p.wihL[i] = f2bf(w - bf2f(h)); }
    { float w = p.w_hh[i]; unsigned short h = f2bf(w); p.whhH[i] = h; p.whhL[i] = f2bf(w - bf2f(h)); }
    if (i < 18432) { float w = p.w1[i]; unsigned short h = f2bf(w); p.w1H[i] = h; p.w1L[i] = f2bf(w - bf2f(h)); }
    if (i < 768) p.bsum[i] = p.b_ih[i] + p.b_hh[i];
  }
  gbar(p);

  // S1: degree count
  for (int e = gtid; e < EB; e += NTHREADS) {
    int dst;
    if (e < BE) { int r = e % EE; int bb = e / EE; dst = p.eidx[EE + r] + bb * NPER; }
    else dst = e - BE;
    atomicAdd(&p.deg[dst], 1);
  }
  gbar(p);

  // S2: scan in block 0 (256 threads x 79 nodes)
  if (b == 0) {
    int* ib = (int*)&sp_lds[0][0][0];
    int s = 0;
    for (int j = 0; j < 79; ++j) {
      int n = tid * 79 + j;
      if (n < NNODES) s += p.deg[n];
    }
    ib[tid] = s;
    __syncthreads();
    for (int off = 1; off < 256; off <<= 1) {
      int tv = (tid >= off) ? ib[tid - off] : 0;
      __syncthreads();
      ib[tid] += tv;
      __syncthreads();
    }
    int excl = ib[tid] - s;
    for (int j = 0; j < 79; ++j) {
      int n = tid * 79 + j;
      if (n < NNODES) { p.startp[n] = excl; excl += p.deg[n]; }
    }
    if (tid == 255) p.startp[NNODES] = ib[255];
  }
  gbar(p);

  // S3: fill adjacency + A(t=0) for all 3 cells
  for (int e = gtid; e < EB; e += NTHREADS) {
    int src, dst;
    if (e < BE) { int r = e % EE; int bb = e / EE; src = p.eidx[r] + bb * NPER; dst = p.eidx[EE + r] + bb * NPER; }
    else { src = e - BE; dst = src; }
    int pos = atomicAdd(&p.cnt[dst], 1);
    p.adj[p.startp[dst] + pos] = src;
  }
  for (int idx = gwid; idx < 3750; idx += NWAVES)
    phaseA(p, idx / 1250, idx % 1250, 0, lane);
  gbar(p);

  // ---- main time loop ----
  for (int t = 0; t < TT; ++t) {
    const bool multi = (t == 0) || (t == 15);
    const int totv = cf * ((t == 0) ? 3 : ((t == 15) ? 2 : 1));
    int nIter = (totv - pb * 2 + SL - 1) / SL;
    if (pb * 2 >= totv) nIter = 0;

    for (int k = 0; k < nIter; ++k) {
      int v = slot + k * SL;
      bool act = v < totv;
      int cell = 0, rb = 0;
      if (act) {
        cell = (v >= cf) + (v >= 2 * cf);
        rb = b0 + v - cell * cf;
        float* sprow0 = &sp_lds[wv >> 1][(wv & 1) * 8][0];
        int nb0 = rb * 16 + (wv & 1) * 8;
        for (int j = 0; j < 8; ++j)
          gather_node(p, cell, t, nb0 + j, lane, sprow0 + j * 68, &al_lds[wv][0], &sr_lds[wv][0]);
      }
      __syncthreads();
      if (act && (wv & 1) == 0) {
        if (cell == 0)
          phaseC_fast(p, rb, t, !multi, lane, &sp_lds[wv >> 1][0][0], &hf_lds[wv >> 1][0][0], creg);
        else
          phaseC_glob(p, cell, rb, lane, &sp_lds[wv >> 1][0][0]);
      }
      __syncthreads();
    }
    // A(t+1) on w1/w3 (fast tiles; + med tiles when t+1==15)
    if ((wv & 1) == 1 && t < TT - 1) {
      int cntA = cf * (((t + 1) == 15) ? 2 : 1);
      for (int vA = slot; vA < cntA; vA += SL) {
        int cellA = (vA >= cf) ? 1 : 0;
        phaseA(p, cellA, b0 + (vA - cellA * cf), t + 1, lane);
      }
    }
    gbar(p);
    if (multi) {
      if ((wv & 1) == 0 && slot < cf)
        mixcore(p, b0 + slot, t, lane, &hf_lds[wv >> 1][0][0]);
      gbar(p);
    }
  }
}

// ---- host side ----
extern "C" void kernel_launch(void* const* d_in, const int* in_sizes, int n_in,
                              void* d_out, int out_size, void* d_ws, size_t ws_size,
                              hipStream_t stream) {
  P p;
  p.x_seq    = (const float*)d_in[0];
  p.lin_w    = (const float*)d_in[1];
  p.att_src  = (const float*)d_in[2];
  p.att_dst  = (const float*)d_in[3];
  p.gat_bias = (const float*)d_in[4];
  p.w_ih     = (const float*)d_in[5];
  p.w_hh     = (const float*)d_in[6];
  p.b_ih     = (const float*)d_in[7];
  p.b_hh     = (const float*)d_in[8];
  p.ln_g     = (const float*)d_in[9];
  p.ln_b     = (const float*)d_in[10];
  p.w1       = (const float*)d_in[11];
  p.b1       = (const float*)d_in[12];
  p.w2       = (const float*)d_in[13];
  p.b2       = (const float*)d_in[14];
  p.eidx     = (const int*)d_in[15];
  p.out      = (float*)d_out;

  char* base = (char*)d_ws;
  size_t off = 0;
  auto alloc = [&](size_t bytes) { char* r = base + off; off += (bytes + 255) & ~(size_t)255; return r; };
  p.xt16  = (unsigned short*)alloc((size_t)6 * 1280000 * 2); // [cell][parity], f16
  p.asrc  = (float*)alloc((size_t)6 * 80000 * 4);
  p.adst  = (float*)alloc((size_t)6 * 80000 * 4);
  p.hHg   = (unsigned short*)alloc((size_t)4 * 1280000 * 2); // hHg[2] + hLg[2] contiguous
  p.hLg   = p.hHg + 2 * 1280000;
  p.cstg  = (float*)alloc((size_t)2 * 1280000 * 4);
  p.bsum  = (float*)alloc(768 * 4);
  p.linH  = (unsigned short*)alloc(12288 * 2);
  p.linL  = (unsigned short*)alloc(12288 * 2);
  p.wihH  = (unsigned short*)alloc(49152 * 2);
  p.wihL  = (unsigned short*)alloc(49152 * 2);
  p.whhH  = (unsigned short*)alloc(49152 * 2);
  p.whhL  = (unsigned short*)alloc(49152 * 2);
  p.w1H   = (unsigned short*)alloc(18432 * 2);
  p.w1L   = (unsigned short*)alloc(18432 * 2);
  p.deg   = (int*)alloc(20008 * 4);
  p.cnt   = (int*)alloc(20008 * 4);
  p.startp= (int*)alloc(20008 * 4);
  p.adj   = (int*)alloc(340000 * 4);
  int* barzone = (int*)alloc(8192);
  p.bar_grp = barzone;
  p.bar_top = barzone + NGRP * 64;
  p.bar_gen = barzone + NGRP * 64 + 16;

  hipMemsetAsync(barzone, 0, 8192, stream);
  mega<<<NB, 256, 0, stream>>>(p);
}

// Round 8
// 2367.368 us; speedup vs baseline: 4.7722x; 1.2105x over previous
//
#include <hip/hip_runtime.h>
#include <cstddef>

#define TT 16
#define EE 80000
#define NB 768
#define HALF_N 2500
#define NCHUNK 157          // ceil(2500/16)
#define NTILE 313           // ceil(5000/16)
#define XT_PAR 320512       // 5008*64
#define AS_PAR 20032        // 5008*4
#define WBLK 258048
#define O_LINH 0
#define O_LINL 12288
#define O_WIHH 24576
#define O_WIHL 73728
#define O_WHHH 122880
#define O_WHHL 172032
#define O_W1H  221184
#define O_W1L  239616
#define XCCREG 6164         // HW_REG_XCC_ID: id=20 | off=0<<6 | (4-1)<<11

typedef __attribute__((ext_vector_type(8))) short bf16x8;
typedef __attribute__((ext_vector_type(4))) float f32x4;

__device__ __forceinline__ float sigf(float x) { return 1.0f / (1.0f + __expf(-x)); }
__device__ __forceinline__ float lreluf(float x) { return x > 0.0f ? x : 0.2f * x; }

__device__ __forceinline__ unsigned short f2bf(float x) {
  union { float f; unsigned u; } v; v.f = x;
  unsigned r = v.u + 0x7FFF + ((v.u >> 16) & 1);
  return (unsigned short)(r >> 16);
}
__device__ __forceinline__ float bf2f(unsigned short u) {
  union { unsigned u; float f; } v; v.u = ((unsigned)u) << 16; return v.f;
}
__device__ __forceinline__ unsigned short f2h(float x) {
  _Float16 h = (_Float16)x;
  return __builtin_bit_cast(unsigned short, h);
}
__device__ __forceinline__ float h2f(unsigned short u) {
  return (float)__builtin_bit_cast(_Float16, u);
}
__device__ __forceinline__ f32x4 mfma16(bf16x8 a, bf16x8 b, f32x4 c) {
  return __builtin_amdgcn_mfma_f32_16x16x32_bf16(a, b, c, 0, 0, 0);
}
__device__ __forceinline__ void split8(const float* s, bf16x8& th, bf16x8& tl) {
#pragma unroll
  for (int i = 0; i < 8; ++i) {
    float v = s[i];
    unsigned short h = f2bf(v);
    th[i] = (short)h;
    tl[i] = (short)f2bf(v - bf2f(h));
  }
}
// sc0 (L1-bypass) loads: coherent within an XCD's L2 without any invalidation
__device__ __forceinline__ unsigned long long ldq(const void* p) {
  return __hip_atomic_load((unsigned long long*)p, __ATOMIC_RELAXED, __HIP_MEMORY_SCOPE_AGENT);
}
__device__ __forceinline__ float ldf(const float* p) {
  return __hip_atomic_load((float*)p, __ATOMIC_RELAXED, __HIP_MEMORY_SCOPE_AGENT);
}
__device__ __forceinline__ int ldi(const int* p) {
  return __hip_atomic_load((int*)p, __ATOMIC_RELAXED, __HIP_MEMORY_SCOPE_AGENT);
}
__device__ __forceinline__ float4 ldv4(const float* p) {
  union { unsigned long long q[2]; float4 v; } u;
  u.q[0] = ldq(p); u.q[1] = ldq(p + 2); return u.v;
}

struct P {
  const float *x_seq, *att_src, *att_dst, *gat_bias, *ln_g, *ln_b, *b1, *w2, *b2;
  const float *lin_w, *w_ih, *w_hh, *b_ih, *b_hh, *w1;
  const int* eidx;
  float* out;
  unsigned short* xt;     // [8][6][XT_PAR]   (cell*2+par)
  float *as, *ad;         // [8][6][AS_PAR]
  float *cmg, *csg;       // [20000*64]
  unsigned short* wblk;   // [8][WBLK]
  float* bsum;            // [8][768]
  int *deg, *cnt, *startp, *adj;   // per-XCD CSR
  int *reg, *gcnt, *ggen, *g0;
};

// ---- fence-free monotonic barrier (blocks of one group, same L2 or device-atomic path) ----
__device__ __forceinline__ void mbar(int* cnt, int* gen, int size, int& rnd) {
  __syncthreads();                 // drains vmcnt of all waves -> stores in L2
  ++rnd;
  if (threadIdx.x == 0) {
    int v = __hip_atomic_fetch_add(cnt, 1, __ATOMIC_RELAXED, __HIP_MEMORY_SCOPE_AGENT) + 1;
    if (v == size * rnd) {
      __hip_atomic_store(gen, rnd, __ATOMIC_RELAXED, __HIP_MEMORY_SCOPE_AGENT);
    } else {
      while (__hip_atomic_load(gen, __ATOMIC_RELAXED, __HIP_MEMORY_SCOPE_AGENT) < rnd)
        __builtin_amdgcn_s_sleep(4);
    }
  }
  __builtin_amdgcn_fence(__ATOMIC_ACQUIRE, "workgroup");   // compiler ordering only
  __syncthreads();
}

// ---- phase A: xt GEMM (split bf16) + attention coefficients (per-XCD private outputs) ----
__device__ void phaseA(const float* xbase, const unsigned short* linH, const unsigned short* linL,
                       const float* attS, const float* attD,
                       unsigned short* xtC, float* asC, float* adC, int rb, int lane) {
  const int l15 = lane & 15, lg = lane >> 4;
  int gm = rb * 16 + l15; if (gm > 4999) gm = 4999;
  const float* arow = xbase + (size_t)gm * 64;
  bf16x8 aH[2], aL[2];
#pragma unroll
  for (int ch = 0; ch < 2; ++ch) {
    float4 u0 = *reinterpret_cast<const float4*>(arow + ch * 32 + lg * 8);
    float4 u1 = *reinterpret_cast<const float4*>(arow + ch * 32 + lg * 8 + 4);
    float v[8] = {u0.x, u0.y, u0.z, u0.w, u1.x, u1.y, u1.z, u1.w};
    bf16x8 th, tl;
#pragma unroll
    for (int i = 0; i < 8; ++i) {
      unsigned short hi = f2bf(v[i]);
      th[i] = (short)hi;
      tl[i] = (short)f2bf(v[i] - bf2f(hi));
    }
    aH[ch] = th; aL[ch] = tl;
  }
  f32x4 acc[4];
#pragma unroll
  for (int nf = 0; nf < 4; ++nf) acc[nf] = (f32x4){0.f, 0.f, 0.f, 0.f};
#pragma unroll
  for (int nf = 0; nf < 4; ++nf) {
#pragma unroll
    for (int ch = 0; ch < 2; ++ch) {
      size_t wo = (size_t)(nf * 16 + l15) * 64 + ch * 32 + lg * 8;
      bf16x8 bH = *reinterpret_cast<const bf16x8*>(linH + wo);
      bf16x8 bL = *reinterpret_cast<const bf16x8*>(linL + wo);
      acc[nf] = mfma16(aH[ch], bH, acc[nf]);
      acc[nf] = mfma16(aH[ch], bL, acc[nf]);
      acc[nf] = mfma16(aL[ch], bH, acc[nf]);
    }
  }
#pragma unroll
  for (int nf = 0; nf < 4; ++nf) {
    float sv = attS[nf * 16 + l15], dv = attD[nf * 16 + l15];
#pragma unroll
    for (int r = 0; r < 4; ++r) {
      int row = rb * 16 + lg * 4 + r;
      float v = acc[nf][r];
      float ps = v * sv, pd = v * dv;
#pragma unroll
      for (int off = 1; off < 16; off <<= 1) { ps += __shfl_xor(ps, off); pd += __shfl_xor(pd, off); }
      xtC[(size_t)row * 64 + nf * 16 + l15] = f2h(v);
      if (l15 == 0) { asC[row * 4 + nf] = ps; adC[row * 4 + nf] = pd; }
    }
  }
}

// ---- gather one node: single-pass softmax, alpha staged in LDS, sc0 reads ----
__device__ void gather_node(const int* startp, const int* adj,
                            const float* asr, const float* adt, const unsigned short* xtC,
                            const float* gbias, int nh, int half, int lane,
                            float* sprow, float* alds, int* slds) {
  int s0 = startp[nh];
  int dg = startp[nh + 1] - s0;
  int nloc = half * 2500 + nh;
  float4 adv = ldv4(adt + (size_t)nloc * 4);

  float ex0 = 0.f, ex1 = 0.f, ex2 = 0.f, ex3 = 0.f;
  int src0 = 0;
  if (lane < dg) {
    src0 = adj[s0 + lane];
    float4 av = ldv4(asr + (size_t)src0 * 4);
    ex0 = __expf(lreluf(av.x + adv.x));
    ex1 = __expf(lreluf(av.y + adv.y));
    ex2 = __expf(lreluf(av.z + adv.z));
    ex3 = __expf(lreluf(av.w + adv.w));
  }
  float dn0 = ex0, dn1 = ex1, dn2 = ex2, dn3 = ex3;
  for (int e = 64 + lane; e < dg; e += 64) {
    int src = adj[s0 + e];
    float4 av = ldv4(asr + (size_t)src * 4);
    dn0 += __expf(lreluf(av.x + adv.x));
    dn1 += __expf(lreluf(av.y + adv.y));
    dn2 += __expf(lreluf(av.z + adv.z));
    dn3 += __expf(lreluf(av.w + adv.w));
  }
#pragma unroll
  for (int off = 1; off < 64; off <<= 1) {
    dn0 += __shfl_xor(dn0, off);
    dn1 += __shfl_xor(dn1, off);
    dn2 += __shfl_xor(dn2, off);
    dn3 += __shfl_xor(dn3, off);
  }
  float rd0 = 1.0f / (dn0 + 1e-16f), rd1 = 1.0f / (dn1 + 1e-16f);
  float rd2 = 1.0f / (dn2 + 1e-16f), rd3 = 1.0f / (dn3 + 1e-16f);
  if (lane < dg) {
    *reinterpret_cast<float4*>(alds + lane * 4) =
        make_float4(ex0 * rd0, ex1 * rd1, ex2 * rd2, ex3 * rd3);
    slds[lane] = src0;
  }
  const int g = lane >> 4, c = lane & 15, head = c >> 2;
  float a0 = 0.f, a1 = 0.f, a2 = 0.f, a3 = 0.f;
  int dglim = dg < 64 ? dg : 64;
  for (int e = g; e < dglim; e += 4) {
    float alpha = alds[e * 4 + head];
    int src = slds[e];
    unsigned long long q = ldq(xtC + (size_t)src * 64 + c * 4);
    a0 = fmaf(alpha, h2f((unsigned short)(q)), a0);
    a1 = fmaf(alpha, h2f((unsigned short)(q >> 16)), a1);
    a2 = fmaf(alpha, h2f((unsigned short)(q >> 32)), a2);
    a3 = fmaf(alpha, h2f((unsigned short)(q >> 48)), a3);
  }
  if (dg > 64) {
    float rdh = head == 0 ? rd0 : head == 1 ? rd1 : head == 2 ? rd2 : rd3;
    float adh = head == 0 ? adv.x : head == 1 ? adv.y : head == 2 ? adv.z : adv.w;
    for (int e = 64 + g; e < dg; e += 4) {
      int src = adj[s0 + e];
      float av = ldf(asr + (size_t)src * 4 + head);
      float alpha = __expf(lreluf(av + adh)) * rdh;
      unsigned long long q = ldq(xtC + (size_t)src * 64 + c * 4);
      a0 = fmaf(alpha, h2f((unsigned short)(q)), a0);
      a1 = fmaf(alpha, h2f((unsigned short)(q >> 16)), a1);
      a2 = fmaf(alpha, h2f((unsigned short)(q >> 32)), a2);
      a3 = fmaf(alpha, h2f((unsigned short)(q >> 48)), a3);
    }
  }
  a0 += __shfl_xor(a0, 16); a0 += __shfl_xor(a0, 32);
  a1 += __shfl_xor(a1, 16); a1 += __shfl_xor(a1, 32);
  a2 += __shfl_xor(a2, 16); a2 += __shfl_xor(a2, 32);
  a3 += __shfl_xor(a3, 16); a3 += __shfl_xor(a3, 32);
  if (g == 0) {
    float4 bz = *reinterpret_cast<const float4*>(gbias + c * 4);
    *reinterpret_cast<float4*>(sprow + c * 4) =
        make_float4(a0 + bz.x, a1 + bz.y, a2 + bz.z, a3 + bz.w);
  }
}

// ---- mix: all three streams split-bf16 from LDS f32; blend exact f32 ----
__device__ void mixcore(const unsigned short* w1H, const unsigned short* w1L,
                        const float* b1, const float* w2, const float* b2, float* out,
                        size_t grow0, int validrows, int t, int lane,
                        const float* hf, const float* hm, const float* hs) {
  const int l15 = lane & 15, lg = lane >> 4;
  bf16x8 aH[3][2], aL[3][2];
#pragma unroll
  for (int ch = 0; ch < 2; ++ch) {
    split8(hf + l15 * 68 + ch * 32 + lg * 8, aH[0][ch], aL[0][ch]);
    split8(hm + l15 * 68 + ch * 32 + lg * 8, aH[1][ch], aL[1][ch]);
    split8(hs + l15 * 68 + ch * 32 + lg * 8, aH[2][ch], aL[2][ch]);
  }
  f32x4 acc[6];
#pragma unroll
  for (int nf = 0; nf < 6; ++nf) acc[nf] = (f32x4){0.f, 0.f, 0.f, 0.f};
#pragma unroll
  for (int nf = 0; nf < 6; ++nf) {
#pragma unroll
    for (int s = 0; s < 3; ++s) {
#pragma unroll
      for (int ch = 0; ch < 2; ++ch) {
        size_t wo = (size_t)(nf * 16 + l15) * 192 + s * 64 + ch * 32 + lg * 8;
        bf16x8 bH = *reinterpret_cast<const bf16x8*>(w1H + wo);
        bf16x8 bL = *reinterpret_cast<const bf16x8*>(w1L + wo);
        acc[nf] = mfma16(aH[s][ch], bH, acc[nf]);
        acc[nf] = mfma16(aH[s][ch], bL, acc[nf]);
        acc[nf] = mfma16(aL[s][ch], bH, acc[nf]);
      }
    }
  }
#pragma unroll
  for (int r = 0; r < 4; ++r) {
    float p0 = 0.f, p1 = 0.f, p2 = 0.f;
#pragma unroll
    for (int nf = 0; nf < 6; ++nf) {
      int n = nf * 16 + l15;
      float hdv = fmaxf(acc[nf][r] + b1[n], 0.f);
      p0 = fmaf(hdv, w2[n], p0);
      p1 = fmaf(hdv, w2[96 + n], p1);
      p2 = fmaf(hdv, w2[192 + n], p2);
    }
#pragma unroll
    for (int off = 1; off < 16; off <<= 1) {
      p0 += __shfl_xor(p0, off); p1 += __shfl_xor(p1, off); p2 += __shfl_xor(p2, off);
    }
    float q0 = p0 + b2[0], q1 = p1 + b2[1], q2 = p2 + b2[2];
    float mx = fmaxf(q0, fmaxf(q1, q2));
    float e0 = __expf(q0 - mx), e1 = __expf(q1 - mx), e2 = __expf(q2 - mx);
    float rs = 1.0f / (e0 + e1 + e2);
    float w0 = e0 * rs, w1v = e1 * rs, w2v = e2 * rs;
    int r16 = lg * 4 + r;
    if (r16 < validrows) {
      size_t ob = ((grow0 + r16) * TT + t) * 64;
#pragma unroll
      for (int q = 0; q < 4; ++q) {
        int col = l15 + 16 * q;
        float vf = hf[r16 * 68 + col];
        float vm = hm[r16 * 68 + col];
        float vs = hs[r16 * 68 + col];
        out[ob + col] = w0 * vf + w1v * vm + w2v * vs;
      }
    }
  }
}

// ---- unified cell update: sp(LDS) + h(LDS) + c(regs or global sc0) ----
__device__ void phaseC(const unsigned short* WihH, const unsigned short* WihL,
                       const unsigned short* WhhH, const unsigned short* WhhL,
                       const float* bsum, const float* lng, const float* lnb,
                       float* cglob, float creg[4][4],
                       size_t grow0, int validrows, int lane,
                       const float* sp, float* h) {
  const int l15 = lane & 15, lg = lane >> 4;
  bf16x8 sH[2], sL[2], hHa[2], hLa[2];
#pragma unroll
  for (int ch = 0; ch < 2; ++ch) {
    split8(sp + l15 * 68 + ch * 32 + lg * 8, sH[ch], sL[ch]);
    split8(h + l15 * 68 + ch * 32 + lg * 8, hHa[ch], hLa[ch]);
  }
  f32x4 acc[16];
#pragma unroll
  for (int nf = 0; nf < 16; ++nf) acc[nf] = (f32x4){0.f, 0.f, 0.f, 0.f};
#pragma unroll
  for (int nf = 0; nf < 16; ++nf) {
#pragma unroll
    for (int ch = 0; ch < 2; ++ch) {
      size_t wo = (size_t)(nf * 16 + l15) * 64 + ch * 32 + lg * 8;
      bf16x8 bH = *reinterpret_cast<const bf16x8*>(WihH + wo);
      bf16x8 bL = *reinterpret_cast<const bf16x8*>(WihL + wo);
      acc[nf] = mfma16(sH[ch], bH, acc[nf]);
      acc[nf] = mfma16(sH[ch], bL, acc[nf]);
      acc[nf] = mfma16(sL[ch], bH, acc[nf]);
      bf16x8 cH = *reinterpret_cast<const bf16x8*>(WhhH + wo);
      bf16x8 cL = *reinterpret_cast<const bf16x8*>(WhhL + wo);
      acc[nf] = mfma16(hHa[ch], cH, acc[nf]);
      acc[nf] = mfma16(hHa[ch], cL, acc[nf]);
      acc[nf] = mfma16(hLa[ch], cH, acc[nf]);
    }
  }
  float hn[4][4];
#pragma unroll
  for (int cq = 0; cq < 4; ++cq) {
    int col = cq * 16 + l15;
    float bi = bsum[col], bff = bsum[64 + col], bg = bsum[128 + col], bo = bsum[192 + col];
#pragma unroll
    for (int r = 0; r < 4; ++r) {
      int r16 = lg * 4 + r;
      float gi = acc[cq][r] + bi;
      float gf = acc[cq + 4][r] + bff;
      float gg = acc[cq + 8][r] + bg;
      float go = acc[cq + 12][r] + bo;
      float cold;
      if (cglob) {
        int crow = r16 < validrows ? r16 : validrows - 1;
        cold = ldf(cglob + (grow0 + crow) * 64 + col);
      } else cold = creg[cq][r];
      float cv = sigf(gf) * cold + sigf(gi) * tanhf(gg);
      if (cglob) { if (r16 < validrows) cglob[(grow0 + r16) * 64 + col] = cv; }
      else creg[cq][r] = cv;
      hn[cq][r] = sigf(go) * tanhf(cv);
    }
  }
#pragma unroll
  for (int r = 0; r < 4; ++r) {
    float s = hn[0][r] + hn[1][r] + hn[2][r] + hn[3][r];
#pragma unroll
    for (int off = 1; off < 16; off <<= 1) s += __shfl_xor(s, off);
    float mu = s * (1.0f / 64.0f);
    float vv = 0.f;
#pragma unroll
    for (int cq = 0; cq < 4; ++cq) { float d = hn[cq][r] - mu; vv += d * d; }
#pragma unroll
    for (int off = 1; off < 16; off <<= 1) vv += __shfl_xor(vv, off);
    float rstd = rsqrtf(vv * (1.0f / 64.0f) + 1e-5f);
#pragma unroll
    for (int cq = 0; cq < 4; ++cq) {
      int col = cq * 16 + l15;
      h[(lg * 4 + r) * 68 + col] = (hn[cq][r] - mu) * rstd * lng[col] + lnb[col];
    }
  }
}

// ---- the mega kernel ----
__global__ __launch_bounds__(256, 3) void mega(P p) {
  const int tid = threadIdx.x, lane = tid & 63, wv = tid >> 6, pair = wv >> 1;
  __shared__ float s8[8][16][68];
  __shared__ float al[4][256];
  __shared__ int sr[4][64];
  __shared__ int shr[2];

  const int xcd = (int)(__builtin_amdgcn_s_getreg(XCCREG) & 7);
  if (tid == 0)
    shr[0] = (int)__hip_atomic_fetch_add(&p.reg[xcd], 1, __ATOMIC_RELAXED, __HIP_MEMORY_SCOPE_AGENT);

  int grnd = 0;
  mbar(p.g0, p.g0 + 16, NB, grnd);     // global: all registrations done
  if (tid == 0) shr[1] = ldi(&p.reg[xcd]);
  __syncthreads();
  const int rank = shr[0], size = shr[1];
  const int batch = xcd >> 1, half = xcd & 1;
  const size_t nodeg = (size_t)batch * 5000 + (size_t)half * 2500;

  unsigned short* xtX = p.xt + (size_t)xcd * 6 * XT_PAR;
  float* asX = p.as + (size_t)xcd * 6 * AS_PAR;
  float* adX = p.ad + (size_t)xcd * 6 * AS_PAR;
  unsigned short* w = p.wblk + (size_t)xcd * WBLK;
  float* bsum = p.bsum + xcd * 768;
  int* deg = p.deg + xcd * 2504;
  int* cnt = p.cnt + xcd * 2504;
  int* startp = p.startp + xcd * 2504;
  int* adj = p.adj + (size_t)xcd * 82504;
  int* xc = p.gcnt + xcd * 16;
  int* xg = p.ggen + xcd * 16;
  int xrnd = 0;

  for (int i = tid; i < 8 * 16 * 68; i += 256) ((float*)s8)[i] = 0.f;
  float creg[4][4];
#pragma unroll
  for (int a = 0; a < 4; ++a)
#pragma unroll
    for (int r = 0; r < 4; ++r) creg[a][r] = 0.f;

  const int st = rank * 256 + tid, stride = size * 256;

  // S0: zero cm/cs (own half) + CSR counters; split weights (private copies)
  for (int i = st; i < 160000; i += stride) {
    p.cmg[nodeg * 64 + i] = 0.f;
    p.csg[nodeg * 64 + i] = 0.f;
  }
  for (int i = st; i < 2504; i += stride) { deg[i] = 0; cnt[i] = 0; }
  for (int i = st; i < 49152; i += stride) {
    if (i < 12288) { float v = p.lin_w[i]; unsigned short h = f2bf(v); w[O_LINH + i] = h; w[O_LINL + i] = f2bf(v - bf2f(h)); }
    { float v = p.w_ih[i]; unsigned short h = f2bf(v); w[O_WIHH + i] = h; w[O_WIHL + i] = f2bf(v - bf2f(h)); }
    { float v = p.w_hh[i]; unsigned short h = f2bf(v); w[O_WHHH + i] = h; w[O_WHHL + i] = f2bf(v - bf2f(h)); }
    if (i < 18432) { float v = p.w1[i]; unsigned short h = f2bf(v); w[O_W1H + i] = h; w[O_W1L + i] = f2bf(v - bf2f(h)); }
    if (i < 768) bsum[i] = p.b_ih[i] + p.b_hh[i];
  }
  mbar(xc, xg, size, xrnd);

  // S1: degree count (edges with dst in my half + self loops)
  for (int i = st; i < EE + 2500; i += stride) {
    if (i < EE) {
      int dst = p.eidx[EE + i];
      if ((dst >= 2500) == (half == 1)) atomicAdd(deg + (dst - half * 2500), 1);
    } else atomicAdd(deg + (i - EE), 1);
  }
  mbar(xc, xg, size, xrnd);

  // S2: scan (rank-0 block of each XCD)
  if (rank == 0) {
    int* ib = (int*)&al[0][0];
    int s = 0;
    for (int j = 0; j < 10; ++j) {
      int n = tid * 10 + j;
      if (n < 2500) s += ldi(deg + n);
    }
    ib[tid] = s;
    __syncthreads();
    for (int off = 1; off < 256; off <<= 1) {
      int tv = (tid >= off) ? ib[tid - off] : 0;
      __syncthreads();
      ib[tid] += tv;
      __syncthreads();
    }
    int excl = ib[tid] - s;
    for (int j = 0; j < 10; ++j) {
      int n = tid * 10 + j;
      if (n < 2500) { startp[n] = excl; excl += ldi(deg + n); }
    }
    if (tid == 255) startp[2500] = ib[255];
    __syncthreads();
  }
  mbar(xc, xg, size, xrnd);

  // S3: fill adjacency + A(t=0) for cells f,m,s
  for (int i = st; i < EE + 2500; i += stride) {
    if (i < EE) {
      int dst = p.eidx[EE + i];
      if ((dst >= 2500) == (half == 1)) {
        int ln = dst - half * 2500;
        int pos = atomicAdd(cnt + ln, 1);
        adj[startp[ln] + pos] = p.eidx[i];
      }
    } else {
      int n = i - EE;
      int pos = atomicAdd(cnt + n, 1);
      adj[startp[n] + pos] = half * 2500 + n;
    }
  }
  {
    const float* xb = p.x_seq + (size_t)batch * 5000 * 64;
    for (int a = rank * 4 + wv; a < 3 * NTILE; a += size * 4) {
      int cell = a / NTILE, rb = a - cell * NTILE;
      phaseA(xb, w + O_LINH + cell * 4096, w + O_LINL + cell * 4096,
             p.att_src + cell * 64, p.att_dst + cell * 64,
             xtX + (size_t)(cell * 2) * XT_PAR, asX + (size_t)(cell * 2) * AS_PAR,
             adX + (size_t)(cell * 2) * AS_PAR, rb, lane);
    }
  }
  mbar(xc, xg, size, xrnd);

  const int chunk = rank * 2 + pair;
  const bool has = chunk < NCHUNK;
  const int validrows = has ? ((2500 - chunk * 16) < 16 ? (2500 - chunk * 16) : 16) : 0;
  const size_t grow0 = nodeg + (size_t)chunk * 16;
  float* sp = &s8[pair * 4 + 0][0][0];
  float* hf = &s8[pair * 4 + 1][0][0];
  float* hm = &s8[pair * 4 + 2][0][0];
  float* hs = &s8[pair * 4 + 3][0][0];

  auto do_gather = [&](int cell, int tstep) {
    if (!has) return;
    int par = tstep & 1;
    const float* asr = asX + (size_t)(cell * 2 + par) * AS_PAR;
    const float* adt = adX + (size_t)(cell * 2 + par) * AS_PAR;
    const unsigned short* xtC = xtX + (size_t)(cell * 2 + par) * XT_PAR;
    const float* gb = p.gat_bias + cell * 64;
    int w01 = wv & 1;
    for (int j = 0; j < 8; ++j) {
      int ridx = w01 * 8 + j;
      int nh = chunk * 16 + ridx;
      float* sprow = sp + ridx * 68;
      if (nh < 2500)
        gather_node(startp, adj, asr, adt, xtC, gb, nh, half, lane, sprow, &al[wv][0], &sr[wv][0]);
      else if ((lane >> 4) == 0)
        *reinterpret_cast<float4*>(sprow + (lane & 15) * 4) = make_float4(0.f, 0.f, 0.f, 0.f);
    }
  };
  auto do_C = [&](int cell, bool domix) {
    if (!has || (wv & 1)) return;
    float* hcur = cell == 0 ? hf : (cell == 1 ? hm : hs);
    float* cg = cell == 0 ? nullptr : (cell == 1 ? p.cmg : p.csg);
    phaseC(w + O_WIHH + cell * 16384, w + O_WIHL + cell * 16384,
           w + O_WHHH + cell * 16384, w + O_WHHL + cell * 16384,
           bsum + cell * 256, p.ln_g + cell * 64, p.ln_b + cell * 64,
           cg, creg, grow0, validrows, lane, sp, hcur);
    if (domix)
      mixcore(w + O_W1H, w + O_W1L, p.b1, p.w2, p.b2, p.out, grow0, validrows,
              0, lane, hf, hm, hs);   // t patched by caller via lambda arg below
  };

  const float* xb = p.x_seq + (size_t)batch * 5000 * 64;

  for (int t = 0; t < TT; ++t) {
    if (t != 0 && t != 15) {
      do_gather(0, t);
      __syncthreads();
      if (wv & 1) {
        int nA = (t + 1 == 15) ? 2 * NTILE : NTILE;
        const float* xbt = xb + (size_t)(t + 1) * 20000 * 64;
        for (int a = rank * 2 + pair; a < nA; a += 2 * size) {
          int cell = a >= NTILE, rb = a - cell * NTILE;
          int par = (t + 1) & 1;
          phaseA(xbt, w + O_LINH + cell * 4096, w + O_LINL + cell * 4096,
                 p.att_src + cell * 64, p.att_dst + cell * 64,
                 xtX + (size_t)(cell * 2 + par) * XT_PAR, asX + (size_t)(cell * 2 + par) * AS_PAR,
                 adX + (size_t)(cell * 2 + par) * AS_PAR, rb, lane);
        }
      } else if (has) {
        phaseC(w + O_WIHH, w + O_WIHL, w + O_WHHH, w + O_WHHL,
               bsum, p.ln_g, p.ln_b, nullptr, creg, grow0, validrows, lane, sp, hf);
        mixcore(w + O_W1H, w + O_W1L, p.b1, p.w2, p.b2, p.out, grow0, validrows, t, lane, hf, hm, hs);
      }
    } else if (t == 0) {
      do_gather(0, 0);
      __syncthreads();
      if (has && !(wv & 1))
        phaseC(w + O_WIHH, w + O_WIHL, w + O_WHHH, w + O_WHHL,
               bsum, p.ln_g, p.ln_b, nullptr, creg, grow0, validrows, lane, sp, hf);
      __syncthreads();
      do_gather(1, 0);
      __syncthreads();
      if (has && !(wv & 1))
        phaseC(w + O_WIHH + 16384, w + O_WIHL + 16384, w + O_WHHH + 16384, w + O_WHHL + 16384,
               bsum + 256, p.ln_g + 64, p.ln_b + 64, p.cmg, creg, grow0, validrows, lane, sp, hm);
      __syncthreads();
      do_gather(2, 0);
      __syncthreads();
      if (has && !(wv & 1)) {
        phaseC(w + O_WIHH + 32768, w + O_WIHL + 32768, w + O_WHHH + 32768, w + O_WHHL + 32768,
               bsum + 512, p.ln_g + 128, p.ln_b + 128, p.csg, creg, grow0, validrows, lane, sp, hs);
        mixcore(w + O_W1H, w + O_W1L, p.b1, p.w2, p.b2, p.out, grow0, validrows, 0, lane, hf, hm, hs);
      }
      __syncthreads();
      const float* xbt = xb + (size_t)20000 * 64;   // t=1
      for (int a = rank * 4 + wv; a < NTILE; a += size * 4)
        phaseA(xbt, w + O_LINH, w + O_LINL, p.att_src, p.att_dst,
               xtX + XT_PAR, asX + AS_PAR, adX + AS_PAR, a, lane);   // cell0, par1
    } else {   // t == 15
      do_gather(0, 15);
      __syncthreads();
      if (has && !(wv & 1))
        phaseC(w + O_WIHH, w + O_WIHL, w + O_WHHH, w + O_WHHL,
               bsum, p.ln_g, p.ln_b, nullptr, creg, grow0, validrows, lane, sp, hf);
      __syncthreads();
      do_gather(1, 15);
      __syncthreads();
      if (has && !(wv & 1)) {
        phaseC(w + O_WIHH + 16384, w + O_WIHL + 16384, w + O_WHHH + 16384, w + O_WHHL + 16384,
               bsum + 256, p.ln_g + 64, p.ln_b + 64, p.cmg, creg, grow0, validrows, lane, sp, hm);
        mixcore(w + O_W1H, w + O_W1L, p.b1, p.w2, p.b2, p.out, grow0, validrows, 15, lane, hf, hm, hs);
      }
    }
    mbar(xc, xg, size, xrnd);
  }
  (void)do_C;
}

// ---- host side ----
extern "C" void kernel_launch(void* const* d_in, const int* in_sizes, int n_in,
                              void* d_out, int out_size, void* d_ws, size_t ws_size,
                              hipStream_t stream) {
  P p;
  p.x_seq    = (const float*)d_in[0];
  p.lin_w    = (const float*)d_in[1];
  p.att_src  = (const float*)d_in[2];
  p.att_dst  = (const float*)d_in[3];
  p.gat_bias = (const float*)d_in[4];
  p.w_ih     = (const float*)d_in[5];
  p.w_hh     = (const float*)d_in[6];
  p.b_ih     = (const float*)d_in[7];
  p.b_hh     = (const float*)d_in[8];
  p.ln_g     = (const float*)d_in[9];
  p.ln_b     = (const float*)d_in[10];
  p.w1       = (const float*)d_in[11];
  p.b1       = (const float*)d_in[12];
  p.w2       = (const float*)d_in[13];
  p.b2       = (const float*)d_in[14];
  p.eidx     = (const int*)d_in[15];
  p.out      = (float*)d_out;

  char* base = (char*)d_ws;
  size_t off = 0;
  auto alloc = [&](size_t bytes) { char* r = base + off; off += (bytes + 255) & ~(size_t)255; return r; };
  p.xt     = (unsigned short*)alloc((size_t)8 * 6 * XT_PAR * 2);
  p.as     = (float*)alloc((size_t)8 * 6 * AS_PAR * 4);
  p.ad     = (float*)alloc((size_t)8 * 6 * AS_PAR * 4);
  p.cmg    = (float*)alloc((size_t)1280000 * 4);
  p.csg    = (float*)alloc((size_t)1280000 * 4);
  p.wblk   = (unsigned short*)alloc((size_t)8 * WBLK * 2);
  p.bsum   = (float*)alloc(8 * 768 * 4);
  p.deg    = (int*)alloc(8 * 2504 * 4);
  p.cnt    = (int*)alloc(8 * 2504 * 4);
  p.startp = (int*)alloc(8 * 2504 * 4);
  p.adj    = (int*)alloc((size_t)8 * 82504 * 4);
  int* barzone = (int*)alloc(8192);
  p.reg  = barzone;            // 8
  p.gcnt = barzone + 64;       // 8*16
  p.ggen = barzone + 64 + 128; // 8*16
  p.g0   = barzone + 64 + 256; // cnt at +0, gen at +16

  hipMemsetAsync(barzone, 0, 8192, stream);
  mega<<<NB, 256, 0, stream>>>(p);
}